// Round 1
// baseline (608.171 us; speedup 1.0000x reference)
//
#include <hip/hip_runtime.h>
#include <cstdint>
#include <cstddef>

typedef __attribute__((ext_vector_type(8))) short short8;
typedef __attribute__((ext_vector_type(4))) float floatx4;

#define DEV static __device__ __forceinline__

// partial-buffer stride: 4096 x 1024 elements
#define PSTRIDE ((size_t)4096 * 1024)

DEV unsigned short f2bf(float f) {
  union { float f; uint32_t u; } v; v.f = f;
  uint32_t r = v.u + 0x7fffu + ((v.u >> 16) & 1u);
  return (unsigned short)(r >> 16);
}
DEV float bf2f(unsigned short h) {
  union { uint32_t u; float f; } v; v.u = ((uint32_t)h) << 16; return v.f;
}
DEV float sigmoidf_(float x) { return 1.f / (1.f + __expf(-x)); }

DEV void gld_lds16(const unsigned short* g, unsigned short* l) {
  __builtin_amdgcn_global_load_lds(
      (const __attribute__((address_space(1))) void*)g,
      (__attribute__((address_space(3))) void*)l, 16, 0, 0);
}

// ---------------------------------------------------------------------------
// fp32 (Kdim x Ndim) row-major -> bf16 (Ndim x Kdim) row-major
// ---------------------------------------------------------------------------
__global__ __launch_bounds__(256) void transpose_kernel(
    const float* __restrict__ W, unsigned short* __restrict__ Wt,
    int Kdim, int Ndim) {
  __shared__ float tile[32][33];
  const int n0 = blockIdx.x * 32;
  const int k0 = blockIdx.y * 32;
  const int tx = threadIdx.x & 31;
  const int ty = threadIdx.x >> 5;
#pragma unroll
  for (int r = 0; r < 32; r += 8)
    tile[ty + r][tx] = W[(size_t)(k0 + ty + r) * Ndim + n0 + tx];
  __syncthreads();
#pragma unroll
  for (int r = 0; r < 32; r += 8)
    Wt[(size_t)(n0 + ty + r) * Kdim + k0 + tx] = f2bf(tile[tx][ty + r]);
}

// flat fp32 -> bf16 cast, 4 elements/thread
__global__ __launch_bounds__(256) void cast_kernel(
    const float* __restrict__ W, unsigned short* __restrict__ Wb) {
  const size_t i = (size_t)blockIdx.x * 256 + threadIdx.x;
  const float4 v = ((const float4*)W)[i];
  ushort4 o;
  o.x = f2bf(v.x); o.y = f2bf(v.y); o.z = f2bf(v.z); o.w = f2bf(v.w);
  ((ushort4*)Wb)[i] = o;
}

// ---------------------------------------------------------------------------
// RMSNorm + u (bf16) + gl logit per row. One block per row.
// ---------------------------------------------------------------------------
__global__ __launch_bounds__(256) void rmsnorm_kernel(
    const float* __restrict__ x, const float* __restrict__ gl_w,
    const float* __restrict__ gl_b, unsigned short* __restrict__ u,
    float* __restrict__ gl_logit) {
  const int row = blockIdx.x;
  const int tid = threadIdx.x;
  const float4 v = ((const float4*)(x + (size_t)row * 1024))[tid];
  float ss = v.x * v.x + v.y * v.y + v.z * v.z + v.w * v.w;
#pragma unroll
  for (int o = 32; o > 0; o >>= 1) ss += __shfl_down(ss, o, 64);
  __shared__ float red[4];
  if ((tid & 63) == 0) red[tid >> 6] = ss;
  __syncthreads();
  const float tot = red[0] + red[1] + red[2] + red[3];
  const float r = rsqrtf(tot * (1.f / 1024.f) + 1e-6f);
  const float ux = v.x * r, uy = v.y * r, uz = v.z * r, uw = v.w * r;
  ushort4 ub;
  ub.x = f2bf(ux); ub.y = f2bf(uy); ub.z = f2bf(uz); ub.w = f2bf(uw);
  ((ushort4*)(u + (size_t)row * 1024))[tid] = ub;
  const float4 w4 = ((const float4*)gl_w)[tid];
  float dot = ux * w4.x + uy * w4.y + uz * w4.z + uw * w4.w;
#pragma unroll
  for (int o = 32; o > 0; o >>= 1) dot += __shfl_down(dot, o, 64);
  __syncthreads();
  if ((tid & 63) == 0) red[tid >> 6] = dot;
  __syncthreads();
  if (tid == 0) gl_logit[row] = red[0] + red[1] + red[2] + red[3] + gl_b[0];
}

// ---------------------------------------------------------------------------
// Direct GEMM: C = A * Bt^T, m97 structure. EPI 2 = bias+silu -> bf16.
// ---------------------------------------------------------------------------
template <int EPI>
__global__ __launch_bounds__(256, 2) void gemm_bt(
    const unsigned short* __restrict__ A, const unsigned short* __restrict__ Bt,
    const float* __restrict__ bias, void* __restrict__ Cout, int Ndim, int Kdim) {
  __shared__ unsigned short As[128 * 32];
  __shared__ unsigned short Bs[128 * 32];
  const int tid = threadIdx.x;
  const int wave = tid >> 6;
  const int lane = tid & 63;
  const size_t row0 = (size_t)blockIdx.x * 128;
  const size_t col0 = (size_t)blockIdx.y * 128;

  const int srow = wave * 32 + (lane >> 2);
  const int kofs = (lane & 3) * 8;
  const unsigned short* pA0 = A + (row0 + srow) * (size_t)Kdim + kofs;
  const unsigned short* pA1 = A + (row0 + srow + 16) * (size_t)Kdim + kofs;
  const unsigned short* pB0 = Bt + (col0 + srow) * (size_t)Kdim + kofs;
  const unsigned short* pB1 = Bt + (col0 + srow + 16) * (size_t)Kdim + kofs;
  unsigned short* lA0 = &As[(wave * 2 + 0) * 512];
  unsigned short* lA1 = &As[(wave * 2 + 1) * 512];
  unsigned short* lB0 = &Bs[(wave * 2 + 0) * 512];
  unsigned short* lB1 = &Bs[(wave * 2 + 1) * 512];

  const int wm = (wave & 1) * 64;
  const int wn = (wave >> 1) * 64;
  const int lr = lane & 15;
  const int lq = lane >> 4;
  const int a_off = (wm + lr) * 32 + lq * 8;
  const int b_off = (wn + lr) * 32 + lq * 8;

  floatx4 acc[4][4];
#pragma unroll
  for (int i = 0; i < 4; i++)
#pragma unroll
    for (int j = 0; j < 4; j++) acc[i][j] = floatx4{0.f, 0.f, 0.f, 0.f};

  for (int kt = 0; kt < Kdim; kt += 32) {
    __syncthreads();
    gld_lds16(pA0, lA0);
    gld_lds16(pA1, lA1);
    gld_lds16(pB0, lB0);
    gld_lds16(pB1, lB1);
    pA0 += 32; pA1 += 32; pB0 += 32; pB1 += 32;
    __syncthreads();
    short8 af[4], bfr[4];
#pragma unroll
    for (int i = 0; i < 4; i++) af[i] = *(const short8*)&As[a_off + i * 16 * 32];
#pragma unroll
    for (int j = 0; j < 4; j++) bfr[j] = *(const short8*)&Bs[b_off + j * 16 * 32];
#pragma unroll
    for (int i = 0; i < 4; i++)
#pragma unroll
      for (int j = 0; j < 4; j++)
        acc[i][j] = __builtin_amdgcn_mfma_f32_16x16x32_bf16(af[i], bfr[j], acc[i][j], 0, 0, 0);
  }

#pragma unroll
  for (int i = 0; i < 4; i++) {
    const size_t rbase = row0 + wm + 16 * i + lq * 4;
#pragma unroll
    for (int j = 0; j < 4; j++) {
      const size_t c = col0 + wn + 16 * j + lr;
#pragma unroll
      for (int r = 0; r < 4; r++) {
        float v = acc[i][j][r];
        const size_t off = (rbase + r) * (size_t)Ndim + c;
        if constexpr (EPI == 2) {
          v += bias[c];
          ((unsigned short*)Cout)[off] = f2bf(v * sigmoidf_(v));
        } else {
          ((unsigned short*)Cout)[off] = f2bf(v);
        }
      }
    }
  }
}

// ---------------------------------------------------------------------------
// Generic split-K GEMM -> bf16 partials at PBase + split*PSTRIDE. N = 1024.
// ---------------------------------------------------------------------------
__global__ __launch_bounds__(256, 2) void gemm_splitkP(
    const unsigned short* __restrict__ A, const unsigned short* __restrict__ Bt,
    unsigned short* __restrict__ PBase, int Kdim, int splitLen) {
  __shared__ unsigned short As[128 * 32];
  __shared__ unsigned short Bs[128 * 32];
  const int split = blockIdx.z;
  const int k0 = split * splitLen;
  const int klen = min(splitLen, Kdim - k0);
  const int tid = threadIdx.x;
  const int wave = tid >> 6;
  const int lane = tid & 63;
  const size_t row0 = (size_t)blockIdx.x * 128;
  const size_t col0 = (size_t)blockIdx.y * 128;

  const int srow = wave * 32 + (lane >> 2);
  const int kofs = (lane & 3) * 8;
  const unsigned short* pA0 = A + (row0 + srow) * (size_t)Kdim + k0 + kofs;
  const unsigned short* pA1 = A + (row0 + srow + 16) * (size_t)Kdim + k0 + kofs;
  const unsigned short* pB0 = Bt + (col0 + srow) * (size_t)Kdim + k0 + kofs;
  const unsigned short* pB1 = Bt + (col0 + srow + 16) * (size_t)Kdim + k0 + kofs;
  unsigned short* lA0 = &As[(wave * 2 + 0) * 512];
  unsigned short* lA1 = &As[(wave * 2 + 1) * 512];
  unsigned short* lB0 = &Bs[(wave * 2 + 0) * 512];
  unsigned short* lB1 = &Bs[(wave * 2 + 1) * 512];

  const int wm = (wave & 1) * 64;
  const int wn = (wave >> 1) * 64;
  const int lr = lane & 15;
  const int lq = lane >> 4;
  const int a_off = (wm + lr) * 32 + lq * 8;
  const int b_off = (wn + lr) * 32 + lq * 8;

  floatx4 acc[4][4];
#pragma unroll
  for (int i = 0; i < 4; i++)
#pragma unroll
    for (int j = 0; j < 4; j++) acc[i][j] = floatx4{0.f, 0.f, 0.f, 0.f};

  for (int kt = 0; kt < klen; kt += 32) {
    __syncthreads();
    gld_lds16(pA0, lA0);
    gld_lds16(pA1, lA1);
    gld_lds16(pB0, lB0);
    gld_lds16(pB1, lB1);
    pA0 += 32; pA1 += 32; pB0 += 32; pB1 += 32;
    __syncthreads();
    short8 af[4], bfr[4];
#pragma unroll
    for (int i = 0; i < 4; i++) af[i] = *(const short8*)&As[a_off + i * 16 * 32];
#pragma unroll
    for (int j = 0; j < 4; j++) bfr[j] = *(const short8*)&Bs[b_off + j * 16 * 32];
#pragma unroll
    for (int i = 0; i < 4; i++)
#pragma unroll
      for (int j = 0; j < 4; j++)
        acc[i][j] = __builtin_amdgcn_mfma_f32_16x16x32_bf16(af[i], bfr[j], acc[i][j], 0, 0, 0);
  }

  unsigned short* P = PBase + (size_t)split * PSTRIDE;
#pragma unroll
  for (int i = 0; i < 4; i++) {
    const size_t rbase = row0 + wm + 16 * i + lq * 4;
#pragma unroll
    for (int j = 0; j < 4; j++) {
      const size_t c = col0 + wn + 16 * j + lr;
#pragma unroll
      for (int r = 0; r < 4; r++)
        P[(rbase + r) * 1024 + c] = f2bf(acc[i][j][r]);
    }
  }
}

// ---------------------------------------------------------------------------
// Batched strided GEMM for composite weights:
//   MT[d_out][kb*1024+d_in] = sum_dmid OT[d_out][kb*1024+dmid]*SB[d_in][kb*1024+dmid]
// ---------------------------------------------------------------------------
__global__ __launch_bounds__(256, 2) void gemm_mt(
    const unsigned short* __restrict__ OT, const unsigned short* __restrict__ SB,
    unsigned short* __restrict__ MT) {
  __shared__ unsigned short As[128 * 32];
  __shared__ unsigned short Bs[128 * 32];
  const int kb = blockIdx.z;
  const int tid = threadIdx.x;
  const int wave = tid >> 6;
  const int lane = tid & 63;
  const size_t row0 = (size_t)blockIdx.x * 128;
  const size_t col0 = (size_t)blockIdx.y * 128;
  const size_t ld = 16384;

  const int srow = wave * 32 + (lane >> 2);
  const int kofs = (lane & 3) * 8;
  const unsigned short* pA0 = OT + (row0 + srow) * ld + kb * 1024 + kofs;
  const unsigned short* pA1 = OT + (row0 + srow + 16) * ld + kb * 1024 + kofs;
  const unsigned short* pB0 = SB + (col0 + srow) * ld + kb * 1024 + kofs;
  const unsigned short* pB1 = SB + (col0 + srow + 16) * ld + kb * 1024 + kofs;
  unsigned short* lA0 = &As[(wave * 2 + 0) * 512];
  unsigned short* lA1 = &As[(wave * 2 + 1) * 512];
  unsigned short* lB0 = &Bs[(wave * 2 + 0) * 512];
  unsigned short* lB1 = &Bs[(wave * 2 + 1) * 512];

  const int wm = (wave & 1) * 64;
  const int wn = (wave >> 1) * 64;
  const int lr = lane & 15;
  const int lq = lane >> 4;
  const int a_off = (wm + lr) * 32 + lq * 8;
  const int b_off = (wn + lr) * 32 + lq * 8;

  floatx4 acc[4][4];
#pragma unroll
  for (int i = 0; i < 4; i++)
#pragma unroll
    for (int j = 0; j < 4; j++) acc[i][j] = floatx4{0.f, 0.f, 0.f, 0.f};

  for (int kt = 0; kt < 1024; kt += 32) {
    __syncthreads();
    gld_lds16(pA0, lA0);
    gld_lds16(pA1, lA1);
    gld_lds16(pB0, lB0);
    gld_lds16(pB1, lB1);
    pA0 += 32; pA1 += 32; pB0 += 32; pB1 += 32;
    __syncthreads();
    short8 af[4], bfr[4];
#pragma unroll
    for (int i = 0; i < 4; i++) af[i] = *(const short8*)&As[a_off + i * 16 * 32];
#pragma unroll
    for (int j = 0; j < 4; j++) bfr[j] = *(const short8*)&Bs[b_off + j * 16 * 32];
#pragma unroll
    for (int i = 0; i < 4; i++)
#pragma unroll
      for (int j = 0; j < 4; j++)
        acc[i][j] = __builtin_amdgcn_mfma_f32_16x16x32_bf16(af[i], bfr[j], acc[i][j], 0, 0, 0);
  }

#pragma unroll
  for (int i = 0; i < 4; i++) {
    const size_t rbase = row0 + wm + 16 * i + lq * 4;
#pragma unroll
    for (int j = 0; j < 4; j++) {
      const size_t c = col0 + wn + 16 * j + lr;
#pragma unroll
      for (int r = 0; r < 4; r++)
        MT[(rbase + r) * ld + kb * 1024 + c] = f2bf(acc[i][j][r]);
    }
  }
}

// ---------------------------------------------------------------------------
// h = conv7(u) * sigmoid(GP0 + GP1 + gate_b)   (gate split-K partials, bf16)
// ---------------------------------------------------------------------------
__global__ __launch_bounds__(256) void convgate2_kernel(
    const unsigned short* __restrict__ u, const float* __restrict__ conv_w,
    const unsigned short* __restrict__ gp, const float* __restrict__ gate_b,
    unsigned short* __restrict__ h) {
  const size_t idx = (size_t)blockIdx.x * 256 + threadIdx.x;
  const int d = (int)(idx & 1023);
  const int t = (int)((idx >> 10) & 2047);
  const unsigned short* up = u + idx;
  float acc = 0.f;
#pragma unroll
  for (int j = 0; j < 7; ++j) {
    const int tt = t - 6 + j;
    if (tt >= 0) acc += conv_w[d * 7 + j] * bf2f(up[(j - 6) * 1024]);
  }
  const float logit = bf2f(gp[idx]) + bf2f(gp[idx + PSTRIDE]) + gate_b[d];
  h[idx] = f2bf(acc * sigmoidf_(logit));
}

// ---------------------------------------------------------------------------
// out = x + (DP0+DP1+DP2+DP3) + down_b    (down split-K partials, bf16)
// ---------------------------------------------------------------------------
__global__ __launch_bounds__(256) void fold4_kernel(
    const float* __restrict__ x, const unsigned short* __restrict__ dp,
    const float* __restrict__ down_b, float* __restrict__ out) {
  const size_t idx = (size_t)blockIdx.x * 256 + threadIdx.x;
  const float s = bf2f(dp[idx]) + bf2f(dp[idx + PSTRIDE]) +
                  bf2f(dp[idx + 2 * PSTRIDE]) + bf2f(dp[idx + 3 * PSTRIDE]);
  out[idx] = x[idx] + s + down_b[idx & 1023];
}

// ---------------------------------------------------------------------------
// out += sigmoid(gl[row]) * (P0+P1+P2)   (sout split-K partials, bf16)
// ---------------------------------------------------------------------------
__global__ __launch_bounds__(256) void reduce3_kernel(
    const unsigned short* __restrict__ p, const float* __restrict__ gl,
    float* __restrict__ out) {
  const size_t idx = (size_t)blockIdx.x * 256 + threadIdx.x;
  const float g = sigmoidf_(gl[idx >> 10]);
  const float s = bf2f(p[idx]) + bf2f(p[idx + PSTRIDE]) + bf2f(p[idx + 2 * PSTRIDE]);
  out[idx] += g * s;
}

// ---------------------------------------------------------------------------
// Chunked scans of u (T=2048, 16 chunks of 128), 16 decay rates each.
// ---------------------------------------------------------------------------
__global__ __launch_bounds__(256) void scan1u_kernel(
    const unsigned short* __restrict__ u, const float* __restrict__ decay_logit,
    float* __restrict__ carry) {
  const int gid = blockIdx.x * 256 + threadIdx.x;  // 0..32767
  const int d = gid & 1023;
  const int b = (gid >> 10) & 1;
  const int c = gid >> 11;
  float a[16], s[16];
#pragma unroll
  for (int k = 0; k < 16; ++k) { a[k] = sigmoidf_(decay_logit[k]); s[k] = 0.f; }
  const unsigned short* p = u + ((size_t)b * 2048 + c * 128) * 1024 + d;
#pragma unroll 2
  for (int t = 0; t < 128; ++t) {
    const float uv = bf2f(*p);
    p += 1024;
#pragma unroll
    for (int k = 0; k < 16; ++k) s[k] = fmaf(a[k], s[k], (1.f - a[k]) * uv);
  }
#pragma unroll
  for (int k = 0; k < 16; ++k)
    carry[(size_t)((c * 2 + b) * 16 + k) * 1024 + d] = s[k];
}

__global__ __launch_bounds__(256) void scan2u_kernel(
    float* __restrict__ carry, const float* __restrict__ decay_logit) {
  const int gid = blockIdx.x * 256 + threadIdx.x;  // 0..32767
  const int d = gid & 1023;
  const int k = (gid >> 10) & 15;
  const int b = gid >> 14;
  const float a = sigmoidf_(decay_logit[k]);
  float aL = a;
#pragma unroll
  for (int i = 0; i < 7; ++i) aL *= aL;  // a^128
  float s = 0.f;
#pragma unroll
  for (int c = 0; c < 16; ++c) {
    const size_t idx = (size_t)((c * 2 + b) * 16 + k) * 1024 + d;
    const float Lc = carry[idx];
    carry[idx] = s;
    s = fmaf(aL, s, Lc);
  }
}

__global__ __launch_bounds__(256) void scan3u_kernel(
    const unsigned short* __restrict__ u, const float* __restrict__ decay_logit,
    const float* __restrict__ carry, unsigned short* __restrict__ Ucat) {
  const int gid = blockIdx.x * 256 + threadIdx.x;  // 0..524287
  const int d = gid & 1023;
  const int k = (gid >> 10) & 15;
  const int b = (gid >> 14) & 1;
  const int c = gid >> 15;
  const float a = sigmoidf_(decay_logit[k]);
  const float na = 1.f - a;
  float s = carry[(size_t)((c * 2 + b) * 16 + k) * 1024 + d];
  const unsigned short* p = u + ((size_t)b * 2048 + c * 128) * 1024 + d;
  unsigned short* q = Ucat + ((size_t)b * 2048 + c * 128) * 16384 + k * 1024 + d;
#pragma unroll 4
  for (int t = 0; t < 128; ++t) {
    s = fmaf(a, s, na * bf2f(*p));
    *q = f2bf(s);
    p += 1024;
    q += 16384;
  }
}

// ---------------------------------------------------------------------------
extern "C" void kernel_launch(void* const* d_in, const int* in_sizes, int n_in,
                              void* d_out, int out_size, void* d_ws,
                              size_t ws_size, hipStream_t stream) {
  const float* x      = (const float*)d_in[0];
  const float* conv_w = (const float*)d_in[1];
  const float* gate_w = (const float*)d_in[2];
  const float* gate_b = (const float*)d_in[3];
  const float* up_w   = (const float*)d_in[4];
  const float* up_b   = (const float*)d_in[5];
  const float* down_w = (const float*)d_in[6];
  const float* down_b = (const float*)d_in[7];
  const float* sin_w  = (const float*)d_in[8];
  const float* sout_w = (const float*)d_in[9];
  const float* decay  = (const float*)d_in[10];
  const float* gl_w   = (const float*)d_in[11];
  const float* gl_b   = (const float*)d_in[12];
  float* out = (float*)d_out;
  char* ws = (char*)d_ws;

  // Workspace (MB offsets), lifetime-overlapped, peak 184 MB + 16 KB (proven):
  //  phase 1 (local path):   GWT@0(2) GP@2(16,2 partials) Hb@18(8) UWT@26(4)
  //                          Mb@30(16) DWT@46(4) DP@50(32,4 partials)
  //  phase 2 (weights):      SB@0(32) OT@32(32)  [after fold]  MT@128(32)
  //  phase 3 (scan+GEMM):    Ucat@0(128)  P@160(24,3 partials)
  //  persistent:             U@160(8, dead after scan3u) CARRY@168(2, dead
  //                          after scan3u) GL@184(16 KB)
  auto Ucat = (unsigned short*)(ws + ((size_t)0 << 20));
  auto GWT  = (unsigned short*)(ws + ((size_t)0 << 20));
  auto GP   = (unsigned short*)(ws + ((size_t)2 << 20));
  auto Hb   = (unsigned short*)(ws + ((size_t)18 << 20));
  auto UWT  = (unsigned short*)(ws + ((size_t)26 << 20));
  auto Mb   = (unsigned short*)(ws + ((size_t)30 << 20));
  auto DWT  = (unsigned short*)(ws + ((size_t)46 << 20));
  auto DP   = (unsigned short*)(ws + ((size_t)50 << 20));
  auto SB   = (unsigned short*)(ws + ((size_t)0 << 20));
  auto OT   = (unsigned short*)(ws + ((size_t)32 << 20));
  auto MT   = (unsigned short*)(ws + ((size_t)128 << 20));
  auto U    = (unsigned short*)(ws + ((size_t)160 << 20));
  auto P    = (unsigned short*)(ws + ((size_t)160 << 20));
  auto CARRY= (float*)(ws + ((size_t)168 << 20));
  auto GL   = (float*)(ws + ((size_t)184 << 20));

  rmsnorm_kernel<<<4096, 256, 0, stream>>>(x, gl_w, gl_b, U, GL);

  // ---- local path (split-K everywhere, bf16 partials, fused reduces) ----
  transpose_kernel<<<dim3(32, 32), 256, 0, stream>>>(gate_w, GWT, 1024, 1024);
  gemm_splitkP<<<dim3(32, 8, 2), 256, 0, stream>>>(U, GWT, GP, 1024, 512);
  convgate2_kernel<<<16384, 256, 0, stream>>>(U, conv_w, GP, gate_b, Hb);
  transpose_kernel<<<dim3(64, 32), 256, 0, stream>>>(up_w, UWT, 1024, 2048);
  gemm_bt<2><<<dim3(32, 16), 256, 0, stream>>>(Hb, UWT, up_b, Mb, 2048, 1024);
  transpose_kernel<<<dim3(32, 64), 256, 0, stream>>>(down_w, DWT, 2048, 1024);
  gemm_splitkP<<<dim3(32, 8, 4), 256, 0, stream>>>(Mb, DWT, DP, 2048, 512);
  fold4_kernel<<<16384, 256, 0, stream>>>(x, DP, down_b, out);

  // ---- composite long-path weights: MT = [sout_k^T @ sin_k^T]_k ----
  cast_kernel<<<16384, 256, 0, stream>>>(sin_w, SB);
  transpose_kernel<<<dim3(32, 512), 256, 0, stream>>>(sout_w, OT, 16384, 1024);
  gemm_mt<<<dim3(8, 8, 16), 256, 0, stream>>>(OT, SB, MT);

  // ---- 16 leaky scans of u -> Ucat (B,T,K*D) ----
  scan1u_kernel<<<128, 256, 0, stream>>>(U, decay, CARRY);
  scan2u_kernel<<<128, 256, 0, stream>>>(CARRY, decay);
  scan3u_kernel<<<2048, 256, 0, stream>>>(U, decay, CARRY, Ucat);

  // ---- long path: split-K x3, bf16 partials, gated reduce ----
  gemm_splitkP<<<dim3(32, 8, 3), 256, 0, stream>>>(Ucat, MT, P, 16384, 5472);
  reduce3_kernel<<<16384, 256, 0, stream>>>(P, GL, out);
}

// Round 2
// 537.060 us; speedup vs baseline: 1.1324x; 1.1324x over previous
//
#include <hip/hip_runtime.h>
#include <cstdint>
#include <cstddef>

typedef __attribute__((ext_vector_type(8))) short short8;
typedef __attribute__((ext_vector_type(4))) float floatx4;

#define DEV static __device__ __forceinline__

// partial-buffer stride: 4096 x 1024 elements
#define PSTRIDE ((size_t)4096 * 1024)

DEV unsigned short f2bf(float f) {
  union { float f; uint32_t u; } v; v.f = f;
  uint32_t r = v.u + 0x7fffu + ((v.u >> 16) & 1u);
  return (unsigned short)(r >> 16);
}
DEV float bf2f(unsigned short h) {
  union { uint32_t u; float f; } v; v.u = ((uint32_t)h) << 16; return v.f;
}
DEV float sigmoidf_(float x) { return 1.f / (1.f + __expf(-x)); }

DEV void gld_lds16(const unsigned short* g, unsigned short* l) {
  __builtin_amdgcn_global_load_lds(
      (const __attribute__((address_space(1))) void*)g,
      (__attribute__((address_space(3))) void*)l, 16, 0, 0);
}

// ---------------------------------------------------------------------------
// fp32 (Kdim x Ndim) row-major -> bf16 (Ndim x Kdim) row-major
// ---------------------------------------------------------------------------
__global__ __launch_bounds__(256) void transpose_kernel(
    const float* __restrict__ W, unsigned short* __restrict__ Wt,
    int Kdim, int Ndim) {
  __shared__ float tile[32][33];
  const int n0 = blockIdx.x * 32;
  const int k0 = blockIdx.y * 32;
  const int tx = threadIdx.x & 31;
  const int ty = threadIdx.x >> 5;
#pragma unroll
  for (int r = 0; r < 32; r += 8)
    tile[ty + r][tx] = W[(size_t)(k0 + ty + r) * Ndim + n0 + tx];
  __syncthreads();
#pragma unroll
  for (int r = 0; r < 32; r += 8)
    Wt[(size_t)(n0 + ty + r) * Kdim + k0 + tx] = f2bf(tile[tx][ty + r]);
}

// flat fp32 -> bf16 cast, 4 elements/thread
__global__ __launch_bounds__(256) void cast_kernel(
    const float* __restrict__ W, unsigned short* __restrict__ Wb) {
  const size_t i = (size_t)blockIdx.x * 256 + threadIdx.x;
  const float4 v = ((const float4*)W)[i];
  ushort4 o;
  o.x = f2bf(v.x); o.y = f2bf(v.y); o.z = f2bf(v.z); o.w = f2bf(v.w);
  ((ushort4*)Wb)[i] = o;
}

// ---------------------------------------------------------------------------
// RMSNorm + u (bf16) + gl logit per row. One block per row.
// ---------------------------------------------------------------------------
__global__ __launch_bounds__(256) void rmsnorm_kernel(
    const float* __restrict__ x, const float* __restrict__ gl_w,
    const float* __restrict__ gl_b, unsigned short* __restrict__ u,
    float* __restrict__ gl_logit) {
  const int row = blockIdx.x;
  const int tid = threadIdx.x;
  const float4 v = ((const float4*)(x + (size_t)row * 1024))[tid];
  float ss = v.x * v.x + v.y * v.y + v.z * v.z + v.w * v.w;
#pragma unroll
  for (int o = 32; o > 0; o >>= 1) ss += __shfl_down(ss, o, 64);
  __shared__ float red[4];
  if ((tid & 63) == 0) red[tid >> 6] = ss;
  __syncthreads();
  const float tot = red[0] + red[1] + red[2] + red[3];
  const float r = rsqrtf(tot * (1.f / 1024.f) + 1e-6f);
  const float ux = v.x * r, uy = v.y * r, uz = v.z * r, uw = v.w * r;
  ushort4 ub;
  ub.x = f2bf(ux); ub.y = f2bf(uy); ub.z = f2bf(uz); ub.w = f2bf(uw);
  ((ushort4*)(u + (size_t)row * 1024))[tid] = ub;
  const float4 w4 = ((const float4*)gl_w)[tid];
  float dot = ux * w4.x + uy * w4.y + uz * w4.z + uw * w4.w;
#pragma unroll
  for (int o = 32; o > 0; o >>= 1) dot += __shfl_down(dot, o, 64);
  __syncthreads();
  if ((tid & 63) == 0) red[tid >> 6] = dot;
  __syncthreads();
  if (tid == 0) gl_logit[row] = red[0] + red[1] + red[2] + red[3] + gl_b[0];
}

// ---------------------------------------------------------------------------
// Direct GEMM: C = A * Bt^T, m97 structure. EPI 2 = bias+silu -> bf16.
// (kept for the "up" GEMM where the 256^2 grid would underfill the GPU)
// ---------------------------------------------------------------------------
template <int EPI>
__global__ __launch_bounds__(256, 2) void gemm_bt(
    const unsigned short* __restrict__ A, const unsigned short* __restrict__ Bt,
    const float* __restrict__ bias, void* __restrict__ Cout, int Ndim, int Kdim) {
  __shared__ unsigned short As[128 * 32];
  __shared__ unsigned short Bs[128 * 32];
  const int tid = threadIdx.x;
  const int wave = tid >> 6;
  const int lane = tid & 63;
  const size_t row0 = (size_t)blockIdx.x * 128;
  const size_t col0 = (size_t)blockIdx.y * 128;

  const int srow = wave * 32 + (lane >> 2);
  const int kofs = (lane & 3) * 8;
  const unsigned short* pA0 = A + (row0 + srow) * (size_t)Kdim + kofs;
  const unsigned short* pA1 = A + (row0 + srow + 16) * (size_t)Kdim + kofs;
  const unsigned short* pB0 = Bt + (col0 + srow) * (size_t)Kdim + kofs;
  const unsigned short* pB1 = Bt + (col0 + srow + 16) * (size_t)Kdim + kofs;
  unsigned short* lA0 = &As[(wave * 2 + 0) * 512];
  unsigned short* lA1 = &As[(wave * 2 + 1) * 512];
  unsigned short* lB0 = &Bs[(wave * 2 + 0) * 512];
  unsigned short* lB1 = &Bs[(wave * 2 + 1) * 512];

  const int wm = (wave & 1) * 64;
  const int wn = (wave >> 1) * 64;
  const int lr = lane & 15;
  const int lq = lane >> 4;
  const int a_off = (wm + lr) * 32 + lq * 8;
  const int b_off = (wn + lr) * 32 + lq * 8;

  floatx4 acc[4][4];
#pragma unroll
  for (int i = 0; i < 4; i++)
#pragma unroll
    for (int j = 0; j < 4; j++) acc[i][j] = floatx4{0.f, 0.f, 0.f, 0.f};

  for (int kt = 0; kt < Kdim; kt += 32) {
    __syncthreads();
    gld_lds16(pA0, lA0);
    gld_lds16(pA1, lA1);
    gld_lds16(pB0, lB0);
    gld_lds16(pB1, lB1);
    pA0 += 32; pA1 += 32; pB0 += 32; pB1 += 32;
    __syncthreads();
    short8 af[4], bfr[4];
#pragma unroll
    for (int i = 0; i < 4; i++) af[i] = *(const short8*)&As[a_off + i * 16 * 32];
#pragma unroll
    for (int j = 0; j < 4; j++) bfr[j] = *(const short8*)&Bs[b_off + j * 16 * 32];
#pragma unroll
    for (int i = 0; i < 4; i++)
#pragma unroll
      for (int j = 0; j < 4; j++)
        acc[i][j] = __builtin_amdgcn_mfma_f32_16x16x32_bf16(af[i], bfr[j], acc[i][j], 0, 0, 0);
  }

#pragma unroll
  for (int i = 0; i < 4; i++) {
    const size_t rbase = row0 + wm + 16 * i + lq * 4;
#pragma unroll
    for (int j = 0; j < 4; j++) {
      const size_t c = col0 + wn + 16 * j + lr;
#pragma unroll
      for (int r = 0; r < 4; r++) {
        float v = acc[i][j][r];
        const size_t off = (rbase + r) * (size_t)Ndim + c;
        if constexpr (EPI == 2) {
          v += bias[c];
          ((unsigned short*)Cout)[off] = f2bf(v * sigmoidf_(v));
        } else {
          ((unsigned short*)Cout)[off] = f2bf(v);
        }
      }
    }
  }
}

// ---------------------------------------------------------------------------
// Generic split-K GEMM -> bf16 partials at PBase + split*PSTRIDE. N = 1024.
// (kept for the "gate" GEMM)
// ---------------------------------------------------------------------------
__global__ __launch_bounds__(256, 2) void gemm_splitkP(
    const unsigned short* __restrict__ A, const unsigned short* __restrict__ Bt,
    unsigned short* __restrict__ PBase, int Kdim, int splitLen) {
  __shared__ unsigned short As[128 * 32];
  __shared__ unsigned short Bs[128 * 32];
  const int split = blockIdx.z;
  const int k0 = split * splitLen;
  const int klen = min(splitLen, Kdim - k0);
  const int tid = threadIdx.x;
  const int wave = tid >> 6;
  const int lane = tid & 63;
  const size_t row0 = (size_t)blockIdx.x * 128;
  const size_t col0 = (size_t)blockIdx.y * 128;

  const int srow = wave * 32 + (lane >> 2);
  const int kofs = (lane & 3) * 8;
  const unsigned short* pA0 = A + (row0 + srow) * (size_t)Kdim + k0 + kofs;
  const unsigned short* pA1 = A + (row0 + srow + 16) * (size_t)Kdim + k0 + kofs;
  const unsigned short* pB0 = Bt + (col0 + srow) * (size_t)Kdim + k0 + kofs;
  const unsigned short* pB1 = Bt + (col0 + srow + 16) * (size_t)Kdim + k0 + kofs;
  unsigned short* lA0 = &As[(wave * 2 + 0) * 512];
  unsigned short* lA1 = &As[(wave * 2 + 1) * 512];
  unsigned short* lB0 = &Bs[(wave * 2 + 0) * 512];
  unsigned short* lB1 = &Bs[(wave * 2 + 1) * 512];

  const int wm = (wave & 1) * 64;
  const int wn = (wave >> 1) * 64;
  const int lr = lane & 15;
  const int lq = lane >> 4;
  const int a_off = (wm + lr) * 32 + lq * 8;
  const int b_off = (wn + lr) * 32 + lq * 8;

  floatx4 acc[4][4];
#pragma unroll
  for (int i = 0; i < 4; i++)
#pragma unroll
    for (int j = 0; j < 4; j++) acc[i][j] = floatx4{0.f, 0.f, 0.f, 0.f};

  for (int kt = 0; kt < klen; kt += 32) {
    __syncthreads();
    gld_lds16(pA0, lA0);
    gld_lds16(pA1, lA1);
    gld_lds16(pB0, lB0);
    gld_lds16(pB1, lB1);
    pA0 += 32; pA1 += 32; pB0 += 32; pB1 += 32;
    __syncthreads();
    short8 af[4], bfr[4];
#pragma unroll
    for (int i = 0; i < 4; i++) af[i] = *(const short8*)&As[a_off + i * 16 * 32];
#pragma unroll
    for (int j = 0; j < 4; j++) bfr[j] = *(const short8*)&Bs[b_off + j * 16 * 32];
#pragma unroll
    for (int i = 0; i < 4; i++)
#pragma unroll
      for (int j = 0; j < 4; j++)
        acc[i][j] = __builtin_amdgcn_mfma_f32_16x16x32_bf16(af[i], bfr[j], acc[i][j], 0, 0, 0);
  }

  unsigned short* P = PBase + (size_t)split * PSTRIDE;
#pragma unroll
  for (int i = 0; i < 4; i++) {
    const size_t rbase = row0 + wm + 16 * i + lq * 4;
#pragma unroll
    for (int j = 0; j < 4; j++) {
      const size_t c = col0 + wn + 16 * j + lr;
#pragma unroll
      for (int r = 0; r < 4; r++)
        P[(rbase + r) * 1024 + c] = f2bf(acc[i][j][r]);
    }
  }
}

// ---------------------------------------------------------------------------
// 256x256-tile 8-phase GEMM (m201 structure: T2 st_16x32 swizzle + T3/T4
// counted vmcnt + T5 setprio). 512 threads = 8 waves (2M x 4N), BK=64,
// 128 KiB LDS double-buffer. C = A * B^T (both A and B row-major, ld = LD).
//   MODE 0: long path.  A=Ucat ld16384, B=MT ld16384, K=16384 split-K via
//           blockIdx.z (splitLen runtime, multiple of 64); out bf16 partial
//           at Cbase + z*PSTRIDE, ldc=1024.
//   MODE 1: composite weights. A=OT, B=SB (ld 16384); z = kb (K=1024 chunk
//           at kb*1024); out MT[row*16384 + z*1024 + col].
//   MODE 2: down GEMM. A=Mb ld2048, B=DWT ld2048, K=2048, z = split of 512;
//           out bf16 partial at Cbase + z*PSTRIDE, ldc=1024.
// Staging: global_load_lds with LINEAR LDS dest; st_16x32 swizzle achieved by
// permuting the per-lane GLOBAL source (lp) and reading at swizzled LDS addr
// (lqs) — same involution both sides (rule 21).
// Schedule per K-tile S (4 phases): phase q reads af rows {2q,2q+1}; bf (all
// 8) read at q=0. Stages: q0/q1 -> tile S+1 A-halves into the other buffer
// (free: S-1's A reads done), q2/q3 -> tile S+2 B-halves into the current
// buffer (free: S's B reads done at q0). vmcnt(4) at q3 = 2 half-tiles in
// flight -> tile S+1 fully landed before its first read. Tail stages clamp
// the source tile (dummy loads into dead regions) so vmcnt counts stay
// uniform with no guards.
// ---------------------------------------------------------------------------
template <int MODE>
__global__ __launch_bounds__(512, 2) void gemm256(
    const unsigned short* __restrict__ A, const unsigned short* __restrict__ B,
    unsigned short* __restrict__ Cbase, int splitLen) {
  __shared__ unsigned short lds[65536];  // 128 KiB: 2 bufs x (A 32KB | B 32KB)
  constexpr int LD = (MODE == 2) ? 2048 : 16384;
  const int tid = threadIdx.x;
  const int w = tid >> 6;
  const int l = tid & 63;
  const int wr = w >> 2;   // 0..1: M 128-block
  const int wc = w & 3;    // 0..3: N 64-block
  const size_t row0 = (size_t)blockIdx.x * 256;
  const size_t col0 = (size_t)blockIdx.y * 256;
  const int z = blockIdx.z;
  int k0, nkt;
  if constexpr (MODE == 0) {
    k0 = z * splitLen;
    int klen = 16384 - k0; if (klen > splitLen) klen = splitLen;
    nkt = klen >> 6;
  } else if constexpr (MODE == 1) {
    k0 = z << 10; nkt = 16;
  } else {
    k0 = z << 9; nkt = 8;
  }

  // staging: lane permutation implements the st_16x32 swizzle on the source
  const int lp = l ^ (((l >> 5) & 1) << 1);
  const unsigned short* gA = A + (row0 + w * 16 + (lp >> 3)) * (size_t)LD + k0 + (lp & 7) * 8;
  const unsigned short* gB = B + (col0 + w * 16 + (lp >> 3)) * (size_t)LD + k0 + (lp & 7) * 8;
  const int sA = w * 1024;           // + buf*32768 + h*8192 (+ i*512), elements
  const int sB = 16384 + w * 1024;

  // fragment-read offsets (elements), swizzle applied via lqs
  const int lr = l & 15;
  const int lq = l >> 4;
  const int lqs = lq ^ (((lr >> 2) & 1) << 1);
  const int aoff = (wr * 128 + lr) * 64 + lqs * 8;          // + buf*32768 + mi*1024 + kk*32
  const int boff = 16384 + (wc * 64 + lr) * 64 + lqs * 8;   // + buf*32768 + nj*1024 + kk*32

#define STG_A(bufb, st, h) { \
    const unsigned short* s_ = gA + (size_t)(h) * (128 * LD) + (size_t)(st) * 64; \
    unsigned short* d_ = &lds[(bufb) * 32768 + (h) * 8192 + sA]; \
    gld_lds16(s_, d_); gld_lds16(s_ + 8 * LD, d_ + 512); }
#define STG_B(bufb, st, h) { \
    const unsigned short* s_ = gB + (size_t)(h) * (128 * LD) + (size_t)(st) * 64; \
    unsigned short* d_ = &lds[(bufb) * 32768 + (h) * 8192 + sB]; \
    gld_lds16(s_, d_); gld_lds16(s_ + 8 * LD, d_ + 512); }

  floatx4 acc[8][4];
#pragma unroll
  for (int i = 0; i < 8; ++i)
#pragma unroll
    for (int j = 0; j < 4; ++j) acc[i][j] = floatx4{0.f, 0.f, 0.f, 0.f};

  // prologue: tile0 complete -> buf0 ; tile1 B halves -> buf1 (A follows in-loop)
  STG_A(0, 0, 0) STG_A(0, 0, 1) STG_B(0, 0, 0) STG_B(0, 0, 1)
  STG_B(1, 1, 0) STG_B(1, 1, 1)
  asm volatile("s_waitcnt vmcnt(4)" ::: "memory");  // tile0's 8 loads landed
  __builtin_amdgcn_s_barrier();

  short8 bfr[4][2];

#define MM2(MI, NJ) \
  acc[MI][NJ] = __builtin_amdgcn_mfma_f32_16x16x32_bf16(af_[(MI) & 1][0], bfr[NJ][0], acc[MI][NJ], 0, 0, 0); \
  acc[MI][NJ] = __builtin_amdgcn_mfma_f32_16x16x32_bf16(af_[(MI) & 1][1], bfr[NJ][1], acc[MI][NJ], 0, 0, 0);

#define PHASE(Q, STAGE_STMT, TAIL) { \
    short8 af_[2][2]; \
    af_[0][0] = *(const short8*)&lds[cb + aoff + (Q * 2 + 0) * 1024]; \
    af_[0][1] = *(const short8*)&lds[cb + aoff + (Q * 2 + 0) * 1024 + 32]; \
    af_[1][0] = *(const short8*)&lds[cb + aoff + (Q * 2 + 1) * 1024]; \
    af_[1][1] = *(const short8*)&lds[cb + aoff + (Q * 2 + 1) * 1024 + 32]; \
    STAGE_STMT \
    __builtin_amdgcn_s_barrier(); \
    asm volatile("s_waitcnt lgkmcnt(0)" ::: "memory"); \
    __builtin_amdgcn_sched_barrier(0); \
    __builtin_amdgcn_s_setprio(1); \
    MM2(Q * 2 + 0, 0) MM2(Q * 2 + 0, 1) MM2(Q * 2 + 0, 2) MM2(Q * 2 + 0, 3) \
    MM2(Q * 2 + 1, 0) MM2(Q * 2 + 1, 1) MM2(Q * 2 + 1, 2) MM2(Q * 2 + 1, 3) \
    __builtin_amdgcn_s_setprio(0); \
    TAIL; \
    __builtin_amdgcn_s_barrier(); }

  for (int S = 0; S < nkt; ++S) {
    const int cur = S & 1;
    const int oth = cur ^ 1;
    const int cb = cur * 32768;
    const int t1 = (S + 1 < nkt) ? S + 1 : nkt - 1;  // clamp: dummy tail stages
    const int t2 = (S + 2 < nkt) ? S + 2 : nkt - 1;
#pragma unroll
    for (int nj = 0; nj < 4; ++nj) {
      bfr[nj][0] = *(const short8*)&lds[cb + boff + nj * 1024];
      bfr[nj][1] = *(const short8*)&lds[cb + boff + nj * 1024 + 32];
    }
    PHASE(0, STG_A(oth, t1, 0), )
    PHASE(1, STG_A(oth, t1, 1), )
    PHASE(2, STG_B(cur, t2, 0), )
    PHASE(3, STG_B(cur, t2, 1), asm volatile("s_waitcnt vmcnt(4)" ::: "memory"))
  }

#pragma unroll
  for (int mi = 0; mi < 8; ++mi) {
    const size_t r0 = row0 + wr * 128 + mi * 16 + lq * 4;
#pragma unroll
    for (int nj = 0; nj < 4; ++nj) {
      const size_t c = col0 + wc * 64 + nj * 16 + lr;
#pragma unroll
      for (int r = 0; r < 4; ++r) {
        const float v = acc[mi][nj][r];
        if constexpr (MODE == 1)
          Cbase[(r0 + r) * 16384 + ((size_t)z << 10) + c] = f2bf(v);
        else
          Cbase[(size_t)z * PSTRIDE + (r0 + r) * 1024 + c] = f2bf(v);
      }
    }
  }
#undef PHASE
#undef MM2
#undef STG_A
#undef STG_B
}

// ---------------------------------------------------------------------------
// h = conv7(u) * sigmoid(GP0 + GP1 + gate_b)   (gate split-K partials, bf16)
// ---------------------------------------------------------------------------
__global__ __launch_bounds__(256) void convgate2_kernel(
    const unsigned short* __restrict__ u, const float* __restrict__ conv_w,
    const unsigned short* __restrict__ gp, const float* __restrict__ gate_b,
    unsigned short* __restrict__ h) {
  const size_t idx = (size_t)blockIdx.x * 256 + threadIdx.x;
  const int d = (int)(idx & 1023);
  const int t = (int)((idx >> 10) & 2047);
  const unsigned short* up = u + idx;
  float acc = 0.f;
#pragma unroll
  for (int j = 0; j < 7; ++j) {
    const int tt = t - 6 + j;
    if (tt >= 0) acc += conv_w[d * 7 + j] * bf2f(up[(j - 6) * 1024]);
  }
  const float logit = bf2f(gp[idx]) + bf2f(gp[idx + PSTRIDE]) + gate_b[d];
  h[idx] = f2bf(acc * sigmoidf_(logit));
}

// ---------------------------------------------------------------------------
// out = x + (DP0+DP1+DP2+DP3) + down_b    (down split-K partials, bf16)
// ---------------------------------------------------------------------------
__global__ __launch_bounds__(256) void fold4_kernel(
    const float* __restrict__ x, const unsigned short* __restrict__ dp,
    const float* __restrict__ down_b, float* __restrict__ out) {
  const size_t idx = (size_t)blockIdx.x * 256 + threadIdx.x;
  const float s = bf2f(dp[idx]) + bf2f(dp[idx + PSTRIDE]) +
                  bf2f(dp[idx + 2 * PSTRIDE]) + bf2f(dp[idx + 3 * PSTRIDE]);
  out[idx] = x[idx] + s + down_b[idx & 1023];
}

// ---------------------------------------------------------------------------
// out += sigmoid(gl[row]) * sum_i P_i   (sout split-K partials, bf16)
// ---------------------------------------------------------------------------
template <int NS>
__global__ __launch_bounds__(256) void reduceNg_kernel(
    const unsigned short* __restrict__ p, const float* __restrict__ gl,
    float* __restrict__ out) {
  const size_t idx = (size_t)blockIdx.x * 256 + threadIdx.x;
  const float g = sigmoidf_(gl[idx >> 10]);
  float s = 0.f;
#pragma unroll
  for (int i = 0; i < NS; ++i) s += bf2f(p[idx + (size_t)i * PSTRIDE]);
  out[idx] += g * s;
}

// ---------------------------------------------------------------------------
// Chunked scans of u (T=2048, 16 chunks of 128), 16 decay rates each.
// ---------------------------------------------------------------------------
__global__ __launch_bounds__(256) void scan1u_kernel(
    const unsigned short* __restrict__ u, const float* __restrict__ decay_logit,
    float* __restrict__ carry) {
  const int gid = blockIdx.x * 256 + threadIdx.x;  // 0..32767
  const int d = gid & 1023;
  const int b = (gid >> 10) & 1;
  const int c = gid >> 11;
  float a[16], s[16];
#pragma unroll
  for (int k = 0; k < 16; ++k) { a[k] = sigmoidf_(decay_logit[k]); s[k] = 0.f; }
  const unsigned short* p = u + ((size_t)b * 2048 + c * 128) * 1024 + d;
#pragma unroll 2
  for (int t = 0; t < 128; ++t) {
    const float uv = bf2f(*p);
    p += 1024;
#pragma unroll
    for (int k = 0; k < 16; ++k) s[k] = fmaf(a[k], s[k], (1.f - a[k]) * uv);
  }
#pragma unroll
  for (int k = 0; k < 16; ++k)
    carry[(size_t)((c * 2 + b) * 16 + k) * 1024 + d] = s[k];
}

__global__ __launch_bounds__(256) void scan2u_kernel(
    float* __restrict__ carry, const float* __restrict__ decay_logit) {
  const int gid = blockIdx.x * 256 + threadIdx.x;  // 0..32767
  const int d = gid & 1023;
  const int k = (gid >> 10) & 15;
  const int b = gid >> 14;
  const float a = sigmoidf_(decay_logit[k]);
  float aL = a;
#pragma unroll
  for (int i = 0; i < 7; ++i) aL *= aL;  // a^128
  float s = 0.f;
#pragma unroll
  for (int c = 0; c < 16; ++c) {
    const size_t idx = (size_t)((c * 2 + b) * 16 + k) * 1024 + d;
    const float Lc = carry[idx];
    carry[idx] = s;
    s = fmaf(aL, s, Lc);
  }
}

__global__ __launch_bounds__(256) void scan3u_kernel(
    const unsigned short* __restrict__ u, const float* __restrict__ decay_logit,
    const float* __restrict__ carry, unsigned short* __restrict__ Ucat) {
  const int gid = blockIdx.x * 256 + threadIdx.x;  // 0..524287
  const int d = gid & 1023;
  const int k = (gid >> 10) & 15;
  const int b = (gid >> 14) & 1;
  const int c = gid >> 15;
  const float a = sigmoidf_(decay_logit[k]);
  const float na = 1.f - a;
  float s = carry[(size_t)((c * 2 + b) * 16 + k) * 1024 + d];
  const unsigned short* p = u + ((size_t)b * 2048 + c * 128) * 1024 + d;
  unsigned short* q = Ucat + ((size_t)b * 2048 + c * 128) * 16384 + k * 1024 + d;
#pragma unroll 4
  for (int t = 0; t < 128; ++t) {
    s = fmaf(a, s, na * bf2f(*p));
    *q = f2bf(s);
    p += 1024;
    q += 16384;
  }
}

// ---------------------------------------------------------------------------
extern "C" void kernel_launch(void* const* d_in, const int* in_sizes, int n_in,
                              void* d_out, int out_size, void* d_ws,
                              size_t ws_size, hipStream_t stream) {
  const float* x      = (const float*)d_in[0];
  const float* conv_w = (const float*)d_in[1];
  const float* gate_w = (const float*)d_in[2];
  const float* gate_b = (const float*)d_in[3];
  const float* up_w   = (const float*)d_in[4];
  const float* up_b   = (const float*)d_in[5];
  const float* down_w = (const float*)d_in[6];
  const float* down_b = (const float*)d_in[7];
  const float* sin_w  = (const float*)d_in[8];
  const float* sout_w = (const float*)d_in[9];
  const float* decay  = (const float*)d_in[10];
  const float* gl_w   = (const float*)d_in[11];
  const float* gl_b   = (const float*)d_in[12];
  float* out = (float*)d_out;
  char* ws = (char*)d_ws;

  // Workspace (MB offsets), lifetime-overlapped:
  //  phase 1 (local path):   GWT@0(2) GP@2(16,2 partials) Hb@18(8) UWT@26(4)
  //                          Mb@30(16) DWT@46(4) DP@50(32,4 partials)
  //  phase 2 (weights):      SB@0(32) OT@32(32)  [after fold]  MT@128(32)
  //  phase 3 (scan+GEMM):    Ucat@0(128)  P@160(NS partials of 8)
  //  persistent:             U@160(8, dead after scan3u) CARRY@168(2, dead
  //                          after scan3u) GL@(192 or 184)(16 KB)
  // Long-path split-K: 4 splits if ws >= 192MB+GL (peak 192MB+16KB), else 3.
  const bool big = ws_size >= (((size_t)192 << 20) + ((size_t)1 << 16));

  auto Ucat = (unsigned short*)(ws + ((size_t)0 << 20));
  auto GWT  = (unsigned short*)(ws + ((size_t)0 << 20));
  auto GP   = (unsigned short*)(ws + ((size_t)2 << 20));
  auto Hb   = (unsigned short*)(ws + ((size_t)18 << 20));
  auto UWT  = (unsigned short*)(ws + ((size_t)26 << 20));
  auto Mb   = (unsigned short*)(ws + ((size_t)30 << 20));
  auto DWT  = (unsigned short*)(ws + ((size_t)46 << 20));
  auto DP   = (unsigned short*)(ws + ((size_t)50 << 20));
  auto SB   = (unsigned short*)(ws + ((size_t)0 << 20));
  auto OT   = (unsigned short*)(ws + ((size_t)32 << 20));
  auto MT   = (unsigned short*)(ws + ((size_t)128 << 20));
  auto U    = (unsigned short*)(ws + ((size_t)160 << 20));
  auto P    = (unsigned short*)(ws + ((size_t)160 << 20));
  auto CARRY= (float*)(ws + ((size_t)168 << 20));
  auto GL   = (float*)(ws + (big ? ((size_t)192 << 20) : ((size_t)184 << 20)));

  rmsnorm_kernel<<<4096, 256, 0, stream>>>(x, gl_w, gl_b, U, GL);

  // ---- local path ----
  transpose_kernel<<<dim3(32, 32), 256, 0, stream>>>(gate_w, GWT, 1024, 1024);
  gemm_splitkP<<<dim3(32, 8, 2), 256, 0, stream>>>(U, GWT, GP, 1024, 512);
  convgate2_kernel<<<16384, 256, 0, stream>>>(U, conv_w, GP, gate_b, Hb);
  transpose_kernel<<<dim3(64, 32), 256, 0, stream>>>(up_w, UWT, 1024, 2048);
  gemm_bt<2><<<dim3(32, 16), 256, 0, stream>>>(Hb, UWT, up_b, Mb, 2048, 1024);
  transpose_kernel<<<dim3(32, 64), 256, 0, stream>>>(down_w, DWT, 2048, 1024);
  gemm256<2><<<dim3(16, 4, 4), 512, 0, stream>>>(Mb, DWT, DP, 512);
  fold4_kernel<<<16384, 256, 0, stream>>>(x, DP, down_b, out);

  // ---- composite long-path weights: MT = [sout_k^T @ sin_k^T]_k ----
  cast_kernel<<<16384, 256, 0, stream>>>(sin_w, SB);
  transpose_kernel<<<dim3(32, 512), 256, 0, stream>>>(sout_w, OT, 16384, 1024);
  gemm256<1><<<dim3(4, 4, 16), 512, 0, stream>>>(OT, SB, MT, 1024);

  // ---- 16 leaky scans of u -> Ucat (B,T,K*D) ----
  scan1u_kernel<<<128, 256, 0, stream>>>(U, decay, CARRY);
  scan2u_kernel<<<128, 256, 0, stream>>>(CARRY, decay);
  scan3u_kernel<<<2048, 256, 0, stream>>>(U, decay, CARRY, Ucat);

  // ---- long path: 256^2 8-phase split-K, bf16 partials, gated reduce ----
  if (big) {
    gemm256<0><<<dim3(16, 4, 4), 512, 0, stream>>>(Ucat, MT, P, 4096);
    reduceNg_kernel<4><<<16384, 256, 0, stream>>>(P, GL, out);
  } else {
    gemm256<0><<<dim3(16, 4, 3), 512, 0, stream>>>(Ucat, MT, P, 5504);
    reduceNg_kernel<3><<<16384, 256, 0, stream>>>(P, GL, out);
  }
}

// Round 3
// 533.356 us; speedup vs baseline: 1.1403x; 1.0069x over previous
//
#include <hip/hip_runtime.h>
#include <cstdint>
#include <cstddef>

typedef __attribute__((ext_vector_type(8))) short short8;
typedef __attribute__((ext_vector_type(4))) float floatx4;

#define DEV static __device__ __forceinline__

// partial-buffer stride: 4096 x 1024 elements
#define PSTRIDE ((size_t)4096 * 1024)

DEV unsigned short f2bf(float f) {
  union { float f; uint32_t u; } v; v.f = f;
  uint32_t r = v.u + 0x7fffu + ((v.u >> 16) & 1u);
  return (unsigned short)(r >> 16);
}
DEV float bf2f(unsigned short h) {
  union { uint32_t u; float f; } v; v.u = ((uint32_t)h) << 16; return v.f;
}
DEV float sigmoidf_(float x) { return 1.f / (1.f + __expf(-x)); }

DEV void gld_lds16(const unsigned short* g, unsigned short* l) {
  __builtin_amdgcn_global_load_lds(
      (const __attribute__((address_space(1))) void*)g,
      (__attribute__((address_space(3))) void*)l, 16, 0, 0);
}

// ---------------------------------------------------------------------------
// fp32 (Kdim x Ndim) row-major -> bf16 (Ndim x Kdim) row-major
// ---------------------------------------------------------------------------
__global__ __launch_bounds__(256) void transpose_kernel(
    const float* __restrict__ W, unsigned short* __restrict__ Wt,
    int Kdim, int Ndim) {
  __shared__ float tile[32][33];
  const int n0 = blockIdx.x * 32;
  const int k0 = blockIdx.y * 32;
  const int tx = threadIdx.x & 31;
  const int ty = threadIdx.x >> 5;
#pragma unroll
  for (int r = 0; r < 32; r += 8)
    tile[ty + r][tx] = W[(size_t)(k0 + ty + r) * Ndim + n0 + tx];
  __syncthreads();
#pragma unroll
  for (int r = 0; r < 32; r += 8)
    Wt[(size_t)(n0 + ty + r) * Kdim + k0 + tx] = f2bf(tile[tx][ty + r]);
}

// flat fp32 -> bf16 cast, 4 elements/thread
__global__ __launch_bounds__(256) void cast_kernel(
    const float* __restrict__ W, unsigned short* __restrict__ Wb) {
  const size_t i = (size_t)blockIdx.x * 256 + threadIdx.x;
  const float4 v = ((const float4*)W)[i];
  ushort4 o;
  o.x = f2bf(v.x); o.y = f2bf(v.y); o.z = f2bf(v.z); o.w = f2bf(v.w);
  ((ushort4*)Wb)[i] = o;
}

// ---------------------------------------------------------------------------
// RMSNorm + u (bf16) + gl logit per row. One block per row.
// ---------------------------------------------------------------------------
__global__ __launch_bounds__(256) void rmsnorm_kernel(
    const float* __restrict__ x, const float* __restrict__ gl_w,
    const float* __restrict__ gl_b, unsigned short* __restrict__ u,
    float* __restrict__ gl_logit) {
  const int row = blockIdx.x;
  const int tid = threadIdx.x;
  const float4 v = ((const float4*)(x + (size_t)row * 1024))[tid];
  float ss = v.x * v.x + v.y * v.y + v.z * v.z + v.w * v.w;
#pragma unroll
  for (int o = 32; o > 0; o >>= 1) ss += __shfl_down(ss, o, 64);
  __shared__ float red[4];
  if ((tid & 63) == 0) red[tid >> 6] = ss;
  __syncthreads();
  const float tot = red[0] + red[1] + red[2] + red[3];
  const float r = rsqrtf(tot * (1.f / 1024.f) + 1e-6f);
  const float ux = v.x * r, uy = v.y * r, uz = v.z * r, uw = v.w * r;
  ushort4 ub;
  ub.x = f2bf(ux); ub.y = f2bf(uy); ub.z = f2bf(uz); ub.w = f2bf(uw);
  ((ushort4*)(u + (size_t)row * 1024))[tid] = ub;
  const float4 w4 = ((const float4*)gl_w)[tid];
  float dot = ux * w4.x + uy * w4.y + uz * w4.z + uw * w4.w;
#pragma unroll
  for (int o = 32; o > 0; o >>= 1) dot += __shfl_down(dot, o, 64);
  __syncthreads();
  if ((tid & 63) == 0) red[tid >> 6] = dot;
  __syncthreads();
  if (tid == 0) gl_logit[row] = red[0] + red[1] + red[2] + red[3] + gl_b[0];
}

// ---------------------------------------------------------------------------
// Direct GEMM: C = A * Bt^T, m97 structure. EPI 2 = bias+silu -> bf16.
// (kept for the "up" GEMM where the 256^2 grid would underfill the GPU)
// ---------------------------------------------------------------------------
template <int EPI>
__global__ __launch_bounds__(256, 2) void gemm_bt(
    const unsigned short* __restrict__ A, const unsigned short* __restrict__ Bt,
    const float* __restrict__ bias, void* __restrict__ Cout, int Ndim, int Kdim) {
  __shared__ unsigned short As[128 * 32];
  __shared__ unsigned short Bs[128 * 32];
  const int tid = threadIdx.x;
  const int wave = tid >> 6;
  const int lane = tid & 63;
  const size_t row0 = (size_t)blockIdx.x * 128;
  const size_t col0 = (size_t)blockIdx.y * 128;

  const int srow = wave * 32 + (lane >> 2);
  const int kofs = (lane & 3) * 8;
  const unsigned short* pA0 = A + (row0 + srow) * (size_t)Kdim + kofs;
  const unsigned short* pA1 = A + (row0 + srow + 16) * (size_t)Kdim + kofs;
  const unsigned short* pB0 = Bt + (col0 + srow) * (size_t)Kdim + kofs;
  const unsigned short* pB1 = Bt + (col0 + srow + 16) * (size_t)Kdim + kofs;
  unsigned short* lA0 = &As[(wave * 2 + 0) * 512];
  unsigned short* lA1 = &As[(wave * 2 + 1) * 512];
  unsigned short* lB0 = &Bs[(wave * 2 + 0) * 512];
  unsigned short* lB1 = &Bs[(wave * 2 + 1) * 512];

  const int wm = (wave & 1) * 64;
  const int wn = (wave >> 1) * 64;
  const int lr = lane & 15;
  const int lq = lane >> 4;
  const int a_off = (wm + lr) * 32 + lq * 8;
  const int b_off = (wn + lr) * 32 + lq * 8;

  floatx4 acc[4][4];
#pragma unroll
  for (int i = 0; i < 4; i++)
#pragma unroll
    for (int j = 0; j < 4; j++) acc[i][j] = floatx4{0.f, 0.f, 0.f, 0.f};

  for (int kt = 0; kt < Kdim; kt += 32) {
    __syncthreads();
    gld_lds16(pA0, lA0);
    gld_lds16(pA1, lA1);
    gld_lds16(pB0, lB0);
    gld_lds16(pB1, lB1);
    pA0 += 32; pA1 += 32; pB0 += 32; pB1 += 32;
    __syncthreads();
    short8 af[4], bfr[4];
#pragma unroll
    for (int i = 0; i < 4; i++) af[i] = *(const short8*)&As[a_off + i * 16 * 32];
#pragma unroll
    for (int j = 0; j < 4; j++) bfr[j] = *(const short8*)&Bs[b_off + j * 16 * 32];
#pragma unroll
    for (int i = 0; i < 4; i++)
#pragma unroll
      for (int j = 0; j < 4; j++)
        acc[i][j] = __builtin_amdgcn_mfma_f32_16x16x32_bf16(af[i], bfr[j], acc[i][j], 0, 0, 0);
  }

#pragma unroll
  for (int i = 0; i < 4; i++) {
    const size_t rbase = row0 + wm + 16 * i + lq * 4;
#pragma unroll
    for (int j = 0; j < 4; j++) {
      const size_t c = col0 + wn + 16 * j + lr;
#pragma unroll
      for (int r = 0; r < 4; r++) {
        float v = acc[i][j][r];
        const size_t off = (rbase + r) * (size_t)Ndim + c;
        if constexpr (EPI == 2) {
          v += bias[c];
          ((unsigned short*)Cout)[off] = f2bf(v * sigmoidf_(v));
        } else {
          ((unsigned short*)Cout)[off] = f2bf(v);
        }
      }
    }
  }
}

// ---------------------------------------------------------------------------
// Generic split-K GEMM -> bf16 partials at PBase + split*PSTRIDE. N = 1024.
// (kept for the "gate" GEMM)
// ---------------------------------------------------------------------------
__global__ __launch_bounds__(256, 2) void gemm_splitkP(
    const unsigned short* __restrict__ A, const unsigned short* __restrict__ Bt,
    unsigned short* __restrict__ PBase, int Kdim, int splitLen) {
  __shared__ unsigned short As[128 * 32];
  __shared__ unsigned short Bs[128 * 32];
  const int split = blockIdx.z;
  const int k0 = split * splitLen;
  const int klen = min(splitLen, Kdim - k0);
  const int tid = threadIdx.x;
  const int wave = tid >> 6;
  const int lane = tid & 63;
  const size_t row0 = (size_t)blockIdx.x * 128;
  const size_t col0 = (size_t)blockIdx.y * 128;

  const int srow = wave * 32 + (lane >> 2);
  const int kofs = (lane & 3) * 8;
  const unsigned short* pA0 = A + (row0 + srow) * (size_t)Kdim + k0 + kofs;
  const unsigned short* pA1 = A + (row0 + srow + 16) * (size_t)Kdim + k0 + kofs;
  const unsigned short* pB0 = Bt + (col0 + srow) * (size_t)Kdim + k0 + kofs;
  const unsigned short* pB1 = Bt + (col0 + srow + 16) * (size_t)Kdim + k0 + kofs;
  unsigned short* lA0 = &As[(wave * 2 + 0) * 512];
  unsigned short* lA1 = &As[(wave * 2 + 1) * 512];
  unsigned short* lB0 = &Bs[(wave * 2 + 0) * 512];
  unsigned short* lB1 = &Bs[(wave * 2 + 1) * 512];

  const int wm = (wave & 1) * 64;
  const int wn = (wave >> 1) * 64;
  const int lr = lane & 15;
  const int lq = lane >> 4;
  const int a_off = (wm + lr) * 32 + lq * 8;
  const int b_off = (wn + lr) * 32 + lq * 8;

  floatx4 acc[4][4];
#pragma unroll
  for (int i = 0; i < 4; i++)
#pragma unroll
    for (int j = 0; j < 4; j++) acc[i][j] = floatx4{0.f, 0.f, 0.f, 0.f};

  for (int kt = 0; kt < klen; kt += 32) {
    __syncthreads();
    gld_lds16(pA0, lA0);
    gld_lds16(pA1, lA1);
    gld_lds16(pB0, lB0);
    gld_lds16(pB1, lB1);
    pA0 += 32; pA1 += 32; pB0 += 32; pB1 += 32;
    __syncthreads();
    short8 af[4], bfr[4];
#pragma unroll
    for (int i = 0; i < 4; i++) af[i] = *(const short8*)&As[a_off + i * 16 * 32];
#pragma unroll
    for (int j = 0; j < 4; j++) bfr[j] = *(const short8*)&Bs[b_off + j * 16 * 32];
#pragma unroll
    for (int i = 0; i < 4; i++)
#pragma unroll
      for (int j = 0; j < 4; j++)
        acc[i][j] = __builtin_amdgcn_mfma_f32_16x16x32_bf16(af[i], bfr[j], acc[i][j], 0, 0, 0);
  }

  unsigned short* P = PBase + (size_t)split * PSTRIDE;
#pragma unroll
  for (int i = 0; i < 4; i++) {
    const size_t rbase = row0 + wm + 16 * i + lq * 4;
#pragma unroll
    for (int j = 0; j < 4; j++) {
      const size_t c = col0 + wn + 16 * j + lr;
#pragma unroll
      for (int r = 0; r < 4; r++)
        P[(rbase + r) * 1024 + c] = f2bf(acc[i][j][r]);
    }
  }
}

// ---------------------------------------------------------------------------
// 256x256-tile 8-phase GEMM (T2 full-XOR swizzle + T3/T4 counted vmcnt + T5
// setprio). 512 threads = 8 waves (2M x 4N), BK=64, 128 KiB LDS dbuf.
// C = A * B^T (A and B row-major, ld = LD).
//   MODE 0: long path (ld 16384, split-K z, out bf16 partial, ldc 1024)
//   MODE 1: composite weights (ld 16384, z = kb chunk, out MT strided)
//   MODE 2: down GEMM (ld 2048, z = split of 512, out bf16 partial)
// LDS swizzle: element offset for (row R, 16B-colblock c) = R*64 + (c ^
// (R&7))*8. Each consecutive 8-lane group of a ds_read_b128 then covers all
// 8 colblocks (32 banks) -> conflict-free. Write side stays LINEAR for
// global_load_lds; the same permutation is applied to the per-lane GLOBAL
// source address (rule 21: both sides, same involution).
// Schedule per K-tile S: bfr (8 reads) at S start; phase q reads af rows
// {2q,2q+1}; stages: q0/q1 -> A(S+1) halves (other buf), q2/q3 -> B(S+2)
// halves (cur buf). vmcnt(4) at q3: A(S+1) landed, B(S+2) 4 loads in
// flight. Tail stages clamp the tile index (dummy re-stage, dead region).
// ---------------------------------------------------------------------------
template <int MODE>
__global__ __launch_bounds__(512, 2) void gemm256(
    const unsigned short* __restrict__ A, const unsigned short* __restrict__ B,
    unsigned short* __restrict__ Cbase, int splitLen) {
  __shared__ unsigned short lds[65536];  // 128 KiB: 2 bufs x (A 32KB | B 32KB)
  constexpr int LD = (MODE == 2) ? 2048 : 16384;
  const int tid = threadIdx.x;
  const int w = tid >> 6;
  const int l = tid & 63;
  const int wr = w >> 2;   // 0..1: M 128-block
  const int wc = w & 3;    // 0..3: N 64-block
  const size_t row0 = (size_t)blockIdx.x * 256;
  const size_t col0 = (size_t)blockIdx.y * 256;
  const int z = blockIdx.z;
  int k0, nkt;
  if constexpr (MODE == 0) {
    k0 = z * splitLen;
    int klen = 16384 - k0; if (klen > splitLen) klen = splitLen;
    nkt = klen >> 6;
  } else if constexpr (MODE == 1) {
    k0 = z << 10; nkt = 16;
  } else {
    k0 = z << 9; nkt = 8;
  }

  // staging: per-lane source permutation implements the full-XOR swizzle
  const int lrow = l >> 3;                      // 0..7 row within 8-row group
  const int lcol = (l & 7) ^ lrow;              // swizzled 16B colblock
  const unsigned short* gA = A + (row0 + w * 16 + lrow) * (size_t)LD + k0 + lcol * 8;
  const unsigned short* gB = B + (col0 + w * 16 + lrow) * (size_t)LD + k0 + lcol * 8;
  const int sA = w * 1024;           // + buf*32768 + h*8192 (+ s*512), elements
  const int sB = 16384 + w * 1024;

  // fragment-read offsets (elements); kk=1 sub-read = offset ^ 32
  const int lr = l & 15;
  const int lq = l >> 4;
  const int aoff = (wr * 128 + lr) * 64 + ((lq ^ (lr & 7)) * 8);        // + buf*32768 + mi*1024
  const int boff = 16384 + (wc * 64 + lr) * 64 + ((lq ^ (lr & 7)) * 8); // + buf*32768 + nj*1024

#define STG_A(bufb, st, h) { \
    const unsigned short* s_ = gA + (size_t)(h) * (128 * LD) + (size_t)(st) * 64; \
    unsigned short* d_ = &lds[(bufb) * 32768 + (h) * 8192 + sA]; \
    gld_lds16(s_, d_); gld_lds16(s_ + 8 * LD, d_ + 512); }
#define STG_B(bufb, st, h) { \
    const unsigned short* s_ = gB + (size_t)(h) * (128 * LD) + (size_t)(st) * 64; \
    unsigned short* d_ = &lds[(bufb) * 32768 + (h) * 8192 + sB]; \
    gld_lds16(s_, d_); gld_lds16(s_ + 8 * LD, d_ + 512); }

  floatx4 acc[8][4];
#pragma unroll
  for (int i = 0; i < 8; ++i)
#pragma unroll
    for (int j = 0; j < 4; ++j) acc[i][j] = floatx4{0.f, 0.f, 0.f, 0.f};

  // prologue: tile0 complete -> buf0 ; tile1 B halves -> buf1 (A follows in-loop)
  STG_A(0, 0, 0) STG_A(0, 0, 1) STG_B(0, 0, 0) STG_B(0, 0, 1)
  STG_B(1, 1, 0) STG_B(1, 1, 1)
  asm volatile("s_waitcnt vmcnt(4)" ::: "memory");  // tile0's 8 loads landed
  __builtin_amdgcn_s_barrier();

  short8 bfr[4][2];

#define MM2(MI, NJ) \
  acc[MI][NJ] = __builtin_amdgcn_mfma_f32_16x16x32_bf16(af_[(MI) & 1][0], bfr[NJ][0], acc[MI][NJ], 0, 0, 0); \
  acc[MI][NJ] = __builtin_amdgcn_mfma_f32_16x16x32_bf16(af_[(MI) & 1][1], bfr[NJ][1], acc[MI][NJ], 0, 0, 0);

#define PHASE(Q, STAGE_STMT, TAIL) { \
    short8 af_[2][2]; \
    af_[0][0] = *(const short8*)&lds[cb + aoff + (Q * 2 + 0) * 1024]; \
    af_[0][1] = *(const short8*)&lds[cb + (aoff ^ 32) + (Q * 2 + 0) * 1024]; \
    af_[1][0] = *(const short8*)&lds[cb + aoff + (Q * 2 + 1) * 1024]; \
    af_[1][1] = *(const short8*)&lds[cb + (aoff ^ 32) + (Q * 2 + 1) * 1024]; \
    STAGE_STMT \
    __builtin_amdgcn_s_barrier(); \
    asm volatile("s_waitcnt lgkmcnt(0)" ::: "memory"); \
    __builtin_amdgcn_sched_barrier(0); \
    __builtin_amdgcn_s_setprio(1); \
    MM2(Q * 2 + 0, 0) MM2(Q * 2 + 0, 1) MM2(Q * 2 + 0, 2) MM2(Q * 2 + 0, 3) \
    MM2(Q * 2 + 1, 0) MM2(Q * 2 + 1, 1) MM2(Q * 2 + 1, 2) MM2(Q * 2 + 1, 3) \
    __builtin_amdgcn_s_setprio(0); \
    TAIL; \
    __builtin_amdgcn_s_barrier(); }

  for (int S = 0; S < nkt; ++S) {
    const int cur = S & 1;
    const int oth = cur ^ 1;
    const int cb = cur * 32768;
    const int t1 = (S + 1 < nkt) ? S + 1 : nkt - 1;  // clamp: dummy tail stages
    const int t2 = (S + 2 < nkt) ? S + 2 : nkt - 1;
#pragma unroll
    for (int nj = 0; nj < 4; ++nj) {
      bfr[nj][0] = *(const short8*)&lds[cb + boff + nj * 1024];
      bfr[nj][1] = *(const short8*)&lds[cb + (boff ^ 32) + nj * 1024];
    }
    PHASE(0, STG_A(oth, t1, 0), )
    PHASE(1, STG_A(oth, t1, 1), )
    PHASE(2, STG_B(cur, t2, 0), )
    PHASE(3, STG_B(cur, t2, 1), asm volatile("s_waitcnt vmcnt(4)" ::: "memory"))
  }

#pragma unroll
  for (int mi = 0; mi < 8; ++mi) {
    const size_t r0 = row0 + wr * 128 + mi * 16 + lq * 4;
#pragma unroll
    for (int nj = 0; nj < 4; ++nj) {
      const size_t c = col0 + wc * 64 + nj * 16 + lr;
#pragma unroll
      for (int r = 0; r < 4; ++r) {
        const float v = acc[mi][nj][r];
        if constexpr (MODE == 1)
          Cbase[(r0 + r) * 16384 + ((size_t)z << 10) + c] = f2bf(v);
        else
          Cbase[(size_t)z * PSTRIDE + (r0 + r) * 1024 + c] = f2bf(v);
      }
    }
  }
#undef PHASE
#undef MM2
#undef STG_A
#undef STG_B
}

// ---------------------------------------------------------------------------
// h = conv7(u) * sigmoid(GP0 + GP1 + gate_b)   (gate split-K partials, bf16)
// ---------------------------------------------------------------------------
__global__ __launch_bounds__(256) void convgate2_kernel(
    const unsigned short* __restrict__ u, const float* __restrict__ conv_w,
    const unsigned short* __restrict__ gp, const float* __restrict__ gate_b,
    unsigned short* __restrict__ h) {
  const size_t idx = (size_t)blockIdx.x * 256 + threadIdx.x;
  const int d = (int)(idx & 1023);
  const int t = (int)((idx >> 10) & 2047);
  const unsigned short* up = u + idx;
  float acc = 0.f;
#pragma unroll
  for (int j = 0; j < 7; ++j) {
    const int tt = t - 6 + j;
    if (tt >= 0) acc += conv_w[d * 7 + j] * bf2f(up[(j - 6) * 1024]);
  }
  const float logit = bf2f(gp[idx]) + bf2f(gp[idx + PSTRIDE]) + gate_b[d];
  h[idx] = f2bf(acc * sigmoidf_(logit));
}

// ---------------------------------------------------------------------------
// out = x + (DP0+DP1+DP2+DP3) + down_b    (down split-K partials, bf16)
// ---------------------------------------------------------------------------
__global__ __launch_bounds__(256) void fold4_kernel(
    const float* __restrict__ x, const unsigned short* __restrict__ dp,
    const float* __restrict__ down_b, float* __restrict__ out) {
  const size_t idx = (size_t)blockIdx.x * 256 + threadIdx.x;
  const float s = bf2f(dp[idx]) + bf2f(dp[idx + PSTRIDE]) +
                  bf2f(dp[idx + 2 * PSTRIDE]) + bf2f(dp[idx + 3 * PSTRIDE]);
  out[idx] = x[idx] + s + down_b[idx & 1023];
}

// ---------------------------------------------------------------------------
// out += sigmoid(gl[row]) * sum_i P_i   (sout split-K partials, bf16)
// ---------------------------------------------------------------------------
template <int NS>
__global__ __launch_bounds__(256) void reduceNg_kernel(
    const unsigned short* __restrict__ p, const float* __restrict__ gl,
    float* __restrict__ out) {
  const size_t idx = (size_t)blockIdx.x * 256 + threadIdx.x;
  const float g = sigmoidf_(gl[idx >> 10]);
  float s = 0.f;
#pragma unroll
  for (int i = 0; i < NS; ++i) s += bf2f(p[idx + (size_t)i * PSTRIDE]);
  out[idx] += g * s;
}

// ---------------------------------------------------------------------------
// Chunked scans of u (T=2048, 16 chunks of 128), 16 decay rates each.
// ---------------------------------------------------------------------------
__global__ __launch_bounds__(256) void scan1u_kernel(
    const unsigned short* __restrict__ u, const float* __restrict__ decay_logit,
    float* __restrict__ carry) {
  const int gid = blockIdx.x * 256 + threadIdx.x;  // 0..32767
  const int d = gid & 1023;
  const int b = (gid >> 10) & 1;
  const int c = gid >> 11;
  float a[16], s[16];
#pragma unroll
  for (int k = 0; k < 16; ++k) { a[k] = sigmoidf_(decay_logit[k]); s[k] = 0.f; }
  const unsigned short* p = u + ((size_t)b * 2048 + c * 128) * 1024 + d;
#pragma unroll 2
  for (int t = 0; t < 128; ++t) {
    const float uv = bf2f(*p);
    p += 1024;
#pragma unroll
    for (int k = 0; k < 16; ++k) s[k] = fmaf(a[k], s[k], (1.f - a[k]) * uv);
  }
#pragma unroll
  for (int k = 0; k < 16; ++k)
    carry[(size_t)((c * 2 + b) * 16 + k) * 1024 + d] = s[k];
}

__global__ __launch_bounds__(256) void scan2u_kernel(
    float* __restrict__ carry, const float* __restrict__ decay_logit) {
  const int gid = blockIdx.x * 256 + threadIdx.x;  // 0..32767
  const int d = gid & 1023;
  const int k = (gid >> 10) & 15;
  const int b = gid >> 14;
  const float a = sigmoidf_(decay_logit[k]);
  float aL = a;
#pragma unroll
  for (int i = 0; i < 7; ++i) aL *= aL;  // a^128
  float s = 0.f;
#pragma unroll
  for (int c = 0; c < 16; ++c) {
    const size_t idx = (size_t)((c * 2 + b) * 16 + k) * 1024 + d;
    const float Lc = carry[idx];
    carry[idx] = s;
    s = fmaf(aL, s, Lc);
  }
}

__global__ __launch_bounds__(256) void scan3u_kernel(
    const unsigned short* __restrict__ u, const float* __restrict__ decay_logit,
    const float* __restrict__ carry, unsigned short* __restrict__ Ucat) {
  const int gid = blockIdx.x * 256 + threadIdx.x;  // 0..524287
  const int d = gid & 1023;
  const int k = (gid >> 10) & 15;
  const int b = (gid >> 14) & 1;
  const int c = gid >> 15;
  const float a = sigmoidf_(decay_logit[k]);
  const float na = 1.f - a;
  float s = carry[(size_t)((c * 2 + b) * 16 + k) * 1024 + d];
  const unsigned short* p = u + ((size_t)b * 2048 + c * 128) * 1024 + d;
  unsigned short* q = Ucat + ((size_t)b * 2048 + c * 128) * 16384 + k * 1024 + d;
#pragma unroll 4
  for (int t = 0; t < 128; ++t) {
    s = fmaf(a, s, na * bf2f(*p));
    *q = f2bf(s);
    p += 1024;
    q += 16384;
  }
}

// ---------------------------------------------------------------------------
extern "C" void kernel_launch(void* const* d_in, const int* in_sizes, int n_in,
                              void* d_out, int out_size, void* d_ws,
                              size_t ws_size, hipStream_t stream) {
  const float* x      = (const float*)d_in[0];
  const float* conv_w = (const float*)d_in[1];
  const float* gate_w = (const float*)d_in[2];
  const float* gate_b = (const float*)d_in[3];
  const float* up_w   = (const float*)d_in[4];
  const float* up_b   = (const float*)d_in[5];
  const float* down_w = (const float*)d_in[6];
  const float* down_b = (const float*)d_in[7];
  const float* sin_w  = (const float*)d_in[8];
  const float* sout_w = (const float*)d_in[9];
  const float* decay  = (const float*)d_in[10];
  const float* gl_w   = (const float*)d_in[11];
  const float* gl_b   = (const float*)d_in[12];
  float* out = (float*)d_out;
  char* ws = (char*)d_ws;

  // Workspace (MB offsets), lifetime-overlapped:
  //  phase 1 (local path):   GWT@0(2) GP@2(16,2 partials) Hb@18(8) UWT@26(4)
  //                          Mb@30(16) DWT@46(4) DP@50(32,4 partials)
  //  phase 2 (weights):      SB@0(32) OT@32(32)  [after fold]  MT@128(32)
  //  phase 3 (scan+GEMM):    Ucat@0(128)  P@160(NS partials of 8)
  //  persistent:             U@160(8, dead after scan3u) CARRY@168(2, dead
  //                          after scan3u) GL@(192 or 184)(16 KB)
  // Long-path split-K: 4 splits if ws >= 192MB+GL (peak 192MB+16KB), else 3.
  const bool big = ws_size >= (((size_t)192 << 20) + ((size_t)1 << 16));

  auto Ucat = (unsigned short*)(ws + ((size_t)0 << 20));
  auto GWT  = (unsigned short*)(ws + ((size_t)0 << 20));
  auto GP   = (unsigned short*)(ws + ((size_t)2 << 20));
  auto Hb   = (unsigned short*)(ws + ((size_t)18 << 20));
  auto UWT  = (unsigned short*)(ws + ((size_t)26 << 20));
  auto Mb   = (unsigned short*)(ws + ((size_t)30 << 20));
  auto DWT  = (unsigned short*)(ws + ((size_t)46 << 20));
  auto DP   = (unsigned short*)(ws + ((size_t)50 << 20));
  auto SB   = (unsigned short*)(ws + ((size_t)0 << 20));
  auto OT   = (unsigned short*)(ws + ((size_t)32 << 20));
  auto MT   = (unsigned short*)(ws + ((size_t)128 << 20));
  auto U    = (unsigned short*)(ws + ((size_t)160 << 20));
  auto P    = (unsigned short*)(ws + ((size_t)160 << 20));
  auto CARRY= (float*)(ws + ((size_t)168 << 20));
  auto GL   = (float*)(ws + (big ? ((size_t)192 << 20) : ((size_t)184 << 20)));

  rmsnorm_kernel<<<4096, 256, 0, stream>>>(x, gl_w, gl_b, U, GL);

  // ---- local path ----
  transpose_kernel<<<dim3(32, 32), 256, 0, stream>>>(gate_w, GWT, 1024, 1024);
  gemm_splitkP<<<dim3(32, 8, 2), 256, 0, stream>>>(U, GWT, GP, 1024, 512);
  convgate2_kernel<<<16384, 256, 0, stream>>>(U, conv_w, GP, gate_b, Hb);
  transpose_kernel<<<dim3(64, 32), 256, 0, stream>>>(up_w, UWT, 1024, 2048);
  gemm_bt<2><<<dim3(32, 16), 256, 0, stream>>>(Hb, UWT, up_b, Mb, 2048, 1024);
  transpose_kernel<<<dim3(32, 64), 256, 0, stream>>>(down_w, DWT, 2048, 1024);
  gemm256<2><<<dim3(16, 4, 4), 512, 0, stream>>>(Mb, DWT, DP, 512);
  fold4_kernel<<<16384, 256, 0, stream>>>(x, DP, down_b, out);

  // ---- composite long-path weights: MT = [sout_k^T @ sin_k^T]_k ----
  cast_kernel<<<16384, 256, 0, stream>>>(sin_w, SB);
  transpose_kernel<<<dim3(32, 512), 256, 0, stream>>>(sout_w, OT, 16384, 1024);
  gemm256<1><<<dim3(4, 4, 16), 512, 0, stream>>>(OT, SB, MT, 1024);

  // ---- 16 leaky scans of u -> Ucat (B,T,K*D) ----
  scan1u_kernel<<<128, 256, 0, stream>>>(U, decay, CARRY);
  scan2u_kernel<<<128, 256, 0, stream>>>(CARRY, decay);
  scan3u_kernel<<<2048, 256, 0, stream>>>(U, decay, CARRY, Ucat);

  // ---- long path: 256^2 8-phase split-K, bf16 partials, gated reduce ----
  if (big) {
    gemm256<0><<<dim3(16, 4, 4), 512, 0, stream>>>(Ucat, MT, P, 4096);
    reduceNg_kernel<4><<<16384, 256, 0, stream>>>(P, GL, out);
  } else {
    gemm256<0><<<dim3(16, 4, 3), 512, 0, stream>>>(Ucat, MT, P, 5504);
    reduceNg_kernel<3><<<16384, 256, 0, stream>>>(P, GL, out);
  }
}

// Round 4
// 527.700 us; speedup vs baseline: 1.1525x; 1.0107x over previous
//
#include <hip/hip_runtime.h>
#include <cstdint>
#include <cstddef>

typedef __attribute__((ext_vector_type(8))) short short8;
typedef __attribute__((ext_vector_type(4))) float floatx4;

#define DEV static __device__ __forceinline__

// partial-buffer stride: 4096 x 1024 elements
#define PSTRIDE ((size_t)4096 * 1024)

DEV unsigned short f2bf(float f) {
  union { float f; uint32_t u; } v; v.f = f;
  uint32_t r = v.u + 0x7fffu + ((v.u >> 16) & 1u);
  return (unsigned short)(r >> 16);
}
DEV float bf2f(unsigned short h) {
  union { uint32_t u; float f; } v; v.u = ((uint32_t)h) << 16; return v.f;
}
DEV float sigmoidf_(float x) { return 1.f / (1.f + __expf(-x)); }

DEV void gld_lds16(const unsigned short* g, unsigned short* l) {
  __builtin_amdgcn_global_load_lds(
      (const __attribute__((address_space(1))) void*)g,
      (__attribute__((address_space(3))) void*)l, 16, 0, 0);
}

// ---------------------------------------------------------------------------
// fp32 (Kdim x Ndim) row-major -> bf16 (Ndim x Kdim) row-major
// ---------------------------------------------------------------------------
__global__ __launch_bounds__(256) void transpose_kernel(
    const float* __restrict__ W, unsigned short* __restrict__ Wt,
    int Kdim, int Ndim) {
  __shared__ float tile[32][33];
  const int n0 = blockIdx.x * 32;
  const int k0 = blockIdx.y * 32;
  const int tx = threadIdx.x & 31;
  const int ty = threadIdx.x >> 5;
#pragma unroll
  for (int r = 0; r < 32; r += 8)
    tile[ty + r][tx] = W[(size_t)(k0 + ty + r) * Ndim + n0 + tx];
  __syncthreads();
#pragma unroll
  for (int r = 0; r < 32; r += 8)
    Wt[(size_t)(n0 + ty + r) * Kdim + k0 + tx] = f2bf(tile[tx][ty + r]);
}

// flat fp32 -> bf16 cast, 4 elements/thread
__global__ __launch_bounds__(256) void cast_kernel(
    const float* __restrict__ W, unsigned short* __restrict__ Wb) {
  const size_t i = (size_t)blockIdx.x * 256 + threadIdx.x;
  const float4 v = ((const float4*)W)[i];
  ushort4 o;
  o.x = f2bf(v.x); o.y = f2bf(v.y); o.z = f2bf(v.z); o.w = f2bf(v.w);
  ((ushort4*)Wb)[i] = o;
}

// ---------------------------------------------------------------------------
// RMSNorm + u (bf16) + gl logit per row. One block per row.
// ---------------------------------------------------------------------------
__global__ __launch_bounds__(256) void rmsnorm_kernel(
    const float* __restrict__ x, const float* __restrict__ gl_w,
    const float* __restrict__ gl_b, unsigned short* __restrict__ u,
    float* __restrict__ gl_logit) {
  const int row = blockIdx.x;
  const int tid = threadIdx.x;
  const float4 v = ((const float4*)(x + (size_t)row * 1024))[tid];
  float ss = v.x * v.x + v.y * v.y + v.z * v.z + v.w * v.w;
#pragma unroll
  for (int o = 32; o > 0; o >>= 1) ss += __shfl_down(ss, o, 64);
  __shared__ float red[4];
  if ((tid & 63) == 0) red[tid >> 6] = ss;
  __syncthreads();
  const float tot = red[0] + red[1] + red[2] + red[3];
  const float r = rsqrtf(tot * (1.f / 1024.f) + 1e-6f);
  const float ux = v.x * r, uy = v.y * r, uz = v.z * r, uw = v.w * r;
  ushort4 ub;
  ub.x = f2bf(ux); ub.y = f2bf(uy); ub.z = f2bf(uz); ub.w = f2bf(uw);
  ((ushort4*)(u + (size_t)row * 1024))[tid] = ub;
  const float4 w4 = ((const float4*)gl_w)[tid];
  float dot = ux * w4.x + uy * w4.y + uz * w4.z + uw * w4.w;
#pragma unroll
  for (int o = 32; o > 0; o >>= 1) dot += __shfl_down(dot, o, 64);
  __syncthreads();
  if ((tid & 63) == 0) red[tid >> 6] = dot;
  __syncthreads();
  if (tid == 0) gl_logit[row] = red[0] + red[1] + red[2] + red[3] + gl_b[0];
}

// ---------------------------------------------------------------------------
// Direct GEMM: C = A * Bt^T, m97 structure. EPI 2 = bias+silu -> bf16.
// (kept for the "up" GEMM where the 256^2 grid would underfill the GPU)
// ---------------------------------------------------------------------------
template <int EPI>
__global__ __launch_bounds__(256, 2) void gemm_bt(
    const unsigned short* __restrict__ A, const unsigned short* __restrict__ Bt,
    const float* __restrict__ bias, void* __restrict__ Cout, int Ndim, int Kdim) {
  __shared__ unsigned short As[128 * 32];
  __shared__ unsigned short Bs[128 * 32];
  const int tid = threadIdx.x;
  const int wave = tid >> 6;
  const int lane = tid & 63;
  const size_t row0 = (size_t)blockIdx.x * 128;
  const size_t col0 = (size_t)blockIdx.y * 128;

  const int srow = wave * 32 + (lane >> 2);
  const int kofs = (lane & 3) * 8;
  const unsigned short* pA0 = A + (row0 + srow) * (size_t)Kdim + kofs;
  const unsigned short* pA1 = A + (row0 + srow + 16) * (size_t)Kdim + kofs;
  const unsigned short* pB0 = Bt + (col0 + srow) * (size_t)Kdim + kofs;
  const unsigned short* pB1 = Bt + (col0 + srow + 16) * (size_t)Kdim + kofs;
  unsigned short* lA0 = &As[(wave * 2 + 0) * 512];
  unsigned short* lA1 = &As[(wave * 2 + 1) * 512];
  unsigned short* lB0 = &Bs[(wave * 2 + 0) * 512];
  unsigned short* lB1 = &Bs[(wave * 2 + 1) * 512];

  const int wm = (wave & 1) * 64;
  const int wn = (wave >> 1) * 64;
  const int lr = lane & 15;
  const int lq = lane >> 4;
  const int a_off = (wm + lr) * 32 + lq * 8;
  const int b_off = (wn + lr) * 32 + lq * 8;

  floatx4 acc[4][4];
#pragma unroll
  for (int i = 0; i < 4; i++)
#pragma unroll
    for (int j = 0; j < 4; j++) acc[i][j] = floatx4{0.f, 0.f, 0.f, 0.f};

  for (int kt = 0; kt < Kdim; kt += 32) {
    __syncthreads();
    gld_lds16(pA0, lA0);
    gld_lds16(pA1, lA1);
    gld_lds16(pB0, lB0);
    gld_lds16(pB1, lB1);
    pA0 += 32; pA1 += 32; pB0 += 32; pB1 += 32;
    __syncthreads();
    short8 af[4], bfr[4];
#pragma unroll
    for (int i = 0; i < 4; i++) af[i] = *(const short8*)&As[a_off + i * 16 * 32];
#pragma unroll
    for (int j = 0; j < 4; j++) bfr[j] = *(const short8*)&Bs[b_off + j * 16 * 32];
#pragma unroll
    for (int i = 0; i < 4; i++)
#pragma unroll
      for (int j = 0; j < 4; j++)
        acc[i][j] = __builtin_amdgcn_mfma_f32_16x16x32_bf16(af[i], bfr[j], acc[i][j], 0, 0, 0);
  }

#pragma unroll
  for (int i = 0; i < 4; i++) {
    const size_t rbase = row0 + wm + 16 * i + lq * 4;
#pragma unroll
    for (int j = 0; j < 4; j++) {
      const size_t c = col0 + wn + 16 * j + lr;
#pragma unroll
      for (int r = 0; r < 4; r++) {
        float v = acc[i][j][r];
        const size_t off = (rbase + r) * (size_t)Ndim + c;
        if constexpr (EPI == 2) {
          v += bias[c];
          ((unsigned short*)Cout)[off] = f2bf(v * sigmoidf_(v));
        } else {
          ((unsigned short*)Cout)[off] = f2bf(v);
        }
      }
    }
  }
}

// ---------------------------------------------------------------------------
// Generic split-K GEMM -> bf16 partials at PBase + split*PSTRIDE. N = 1024.
// (kept for the "gate" GEMM)
// ---------------------------------------------------------------------------
__global__ __launch_bounds__(256, 2) void gemm_splitkP(
    const unsigned short* __restrict__ A, const unsigned short* __restrict__ Bt,
    unsigned short* __restrict__ PBase, int Kdim, int splitLen) {
  __shared__ unsigned short As[128 * 32];
  __shared__ unsigned short Bs[128 * 32];
  const int split = blockIdx.z;
  const int k0 = split * splitLen;
  const int klen = min(splitLen, Kdim - k0);
  const int tid = threadIdx.x;
  const int wave = tid >> 6;
  const int lane = tid & 63;
  const size_t row0 = (size_t)blockIdx.x * 128;
  const size_t col0 = (size_t)blockIdx.y * 128;

  const int srow = wave * 32 + (lane >> 2);
  const int kofs = (lane & 3) * 8;
  const unsigned short* pA0 = A + (row0 + srow) * (size_t)Kdim + k0 + kofs;
  const unsigned short* pA1 = A + (row0 + srow + 16) * (size_t)Kdim + k0 + kofs;
  const unsigned short* pB0 = Bt + (col0 + srow) * (size_t)Kdim + k0 + kofs;
  const unsigned short* pB1 = Bt + (col0 + srow + 16) * (size_t)Kdim + k0 + kofs;
  unsigned short* lA0 = &As[(wave * 2 + 0) * 512];
  unsigned short* lA1 = &As[(wave * 2 + 1) * 512];
  unsigned short* lB0 = &Bs[(wave * 2 + 0) * 512];
  unsigned short* lB1 = &Bs[(wave * 2 + 1) * 512];

  const int wm = (wave & 1) * 64;
  const int wn = (wave >> 1) * 64;
  const int lr = lane & 15;
  const int lq = lane >> 4;
  const int a_off = (wm + lr) * 32 + lq * 8;
  const int b_off = (wn + lr) * 32 + lq * 8;

  floatx4 acc[4][4];
#pragma unroll
  for (int i = 0; i < 4; i++)
#pragma unroll
    for (int j = 0; j < 4; j++) acc[i][j] = floatx4{0.f, 0.f, 0.f, 0.f};

  for (int kt = 0; kt < klen; kt += 32) {
    __syncthreads();
    gld_lds16(pA0, lA0);
    gld_lds16(pA1, lA1);
    gld_lds16(pB0, lB0);
    gld_lds16(pB1, lB1);
    pA0 += 32; pA1 += 32; pB0 += 32; pB1 += 32;
    __syncthreads();
    short8 af[4], bfr[4];
#pragma unroll
    for (int i = 0; i < 4; i++) af[i] = *(const short8*)&As[a_off + i * 16 * 32];
#pragma unroll
    for (int j = 0; j < 4; j++) bfr[j] = *(const short8*)&Bs[b_off + j * 16 * 32];
#pragma unroll
    for (int i = 0; i < 4; i++)
#pragma unroll
      for (int j = 0; j < 4; j++)
        acc[i][j] = __builtin_amdgcn_mfma_f32_16x16x32_bf16(af[i], bfr[j], acc[i][j], 0, 0, 0);
  }

  unsigned short* P = PBase + (size_t)split * PSTRIDE;
#pragma unroll
  for (int i = 0; i < 4; i++) {
    const size_t rbase = row0 + wm + 16 * i + lq * 4;
#pragma unroll
    for (int j = 0; j < 4; j++) {
      const size_t c = col0 + wn + 16 * j + lr;
#pragma unroll
      for (int r = 0; r < 4; r++)
        P[(rbase + r) * 1024 + c] = f2bf(acc[i][j][r]);
    }
  }
}

// ---------------------------------------------------------------------------
// 256x256-tile 8-phase GEMM. T2 full-XOR swizzle (conflict-free, verified r3:
// SQ_LDS_BANK_CONFLICT=0) + T3/T4 counted vmcnt + T5 setprio + NEW (r4):
// cross-phase ds_read/MFMA overlap via af double-buffer and counted lgkmcnt.
// 512 threads = 8 waves (2M x 4N), BK=64, 128 KiB LDS dbuf. C = A * B^T.
//   MODE 0: long path (ld 16384, split-K z, out bf16 partial, ldc 1024)
//   MODE 1: composite weights (ld 16384, z = kb chunk, out MT strided)
//   MODE 2: down GEMM (ld 2048, z = split of 512, out bf16 partial)
// LDS swizzle: element offset for (row R, 16B-colblock c) = R*64 + (c ^
// (R&7))*8; write side = linear LDS dest + permuted per-lane global source.
// Schedule per K-tile S (phases q0..q3, rows 2q,2q+1):
//   tile-top: issue af(rows0,1)->afA (4 ds) + bfr[0..3] (8 ds)
//   q0: STG_A(S+1,h0); issue af(2,3)->afB; barrier; stepped lgkmcnt
//       10/8/6/4 with nj-ordered MFMA (early start: first MFMA needs only
//       6 reads); MFMA rows0-1; barrier
//   q1: STG_A(S+1,h1); issue af(4,5)->afA; barrier; lgkmcnt(4); MFMA rows2-3
//   q2: STG_B(S+2,h0); issue af(6,7)->afB; barrier; lgkmcnt(4); MFMA rows4-5
//   q3: STG_B(S+2,h1); barrier; lgkmcnt(0); MFMA rows6-7; vmcnt(4); barrier
// lgkmcnt counts ds ops only (global_load_lds is vmcnt-domain), so the
// counted waits drain exactly the previous phase's af reads while allowing
// the next phase's 4 to stay in flight -> LDS pipe overlaps MFMA pipe.
// Cross-wave safety unchanged: staged buffers only read after the TAIL
// vmcnt(4)+barrier of the tile that staged them (A) / two tiles prior (B);
// in-tile ds_reads always drain >=2 barriers before any overwrite issue.
// ---------------------------------------------------------------------------
template <int MODE>
__global__ __launch_bounds__(512, 2) void gemm256(
    const unsigned short* __restrict__ A, const unsigned short* __restrict__ B,
    unsigned short* __restrict__ Cbase, int splitLen) {
  __shared__ unsigned short lds[65536];  // 128 KiB: 2 bufs x (A 32KB | B 32KB)
  constexpr int LD = (MODE == 2) ? 2048 : 16384;
  const int tid = threadIdx.x;
  const int w = tid >> 6;
  const int l = tid & 63;
  const int wr = w >> 2;   // 0..1: M 128-block
  const int wc = w & 3;    // 0..3: N 64-block
  const size_t row0 = (size_t)blockIdx.x * 256;
  const size_t col0 = (size_t)blockIdx.y * 256;
  const int z = blockIdx.z;
  int k0, nkt;
  if constexpr (MODE == 0) {
    k0 = z * splitLen;
    int klen = 16384 - k0; if (klen > splitLen) klen = splitLen;
    nkt = klen >> 6;
  } else if constexpr (MODE == 1) {
    k0 = z << 10; nkt = 16;
  } else {
    k0 = z << 9; nkt = 8;
  }

  // staging: per-lane source permutation implements the full-XOR swizzle
  const int lrow = l >> 3;                      // 0..7 row within 8-row group
  const int lcol = (l & 7) ^ lrow;              // swizzled 16B colblock
  const unsigned short* gA = A + (row0 + w * 16 + lrow) * (size_t)LD + k0 + lcol * 8;
  const unsigned short* gB = B + (col0 + w * 16 + lrow) * (size_t)LD + k0 + lcol * 8;
  const int sA = w * 1024;           // + buf*32768 + h*8192 (+ s*512), elements
  const int sB = 16384 + w * 1024;

  // fragment-read offsets (elements); kk=1 sub-read = offset ^ 32
  const int lr = l & 15;
  const int lq = l >> 4;
  const int aoff = (wr * 128 + lr) * 64 + ((lq ^ (lr & 7)) * 8);        // + buf*32768 + mi*1024
  const int boff = 16384 + (wc * 64 + lr) * 64 + ((lq ^ (lr & 7)) * 8); // + buf*32768 + nj*1024

#define STG_A(bufb, st, h) { \
    const unsigned short* s_ = gA + (size_t)(h) * (128 * LD) + (size_t)(st) * 64; \
    unsigned short* d_ = &lds[(bufb) * 32768 + (h) * 8192 + sA]; \
    gld_lds16(s_, d_); gld_lds16(s_ + 8 * LD, d_ + 512); }
#define STG_B(bufb, st, h) { \
    const unsigned short* s_ = gB + (size_t)(h) * (128 * LD) + (size_t)(st) * 64; \
    unsigned short* d_ = &lds[(bufb) * 32768 + (h) * 8192 + sB]; \
    gld_lds16(s_, d_); gld_lds16(s_ + 8 * LD, d_ + 512); }

  floatx4 acc[8][4];
#pragma unroll
  for (int i = 0; i < 8; ++i)
#pragma unroll
    for (int j = 0; j < 4; ++j) acc[i][j] = floatx4{0.f, 0.f, 0.f, 0.f};

  // prologue: tile0 complete -> buf0 ; tile1 B halves -> buf1 (A follows in-loop)
  STG_A(0, 0, 0) STG_A(0, 0, 1) STG_B(0, 0, 0) STG_B(0, 0, 1)
  STG_B(1, 1, 0) STG_B(1, 1, 1)
  asm volatile("s_waitcnt vmcnt(4)" ::: "memory");  // tile0's 8 loads landed
  __builtin_amdgcn_s_barrier();

  short8 bfr[4][2];
  short8 afA[2][2], afB[2][2];

#define LD_AF(DST, MI) \
    DST[0][0] = *(const short8*)&lds[cb + aoff + (MI) * 1024]; \
    DST[0][1] = *(const short8*)&lds[cb + (aoff ^ 32) + (MI) * 1024]; \
    DST[1][0] = *(const short8*)&lds[cb + aoff + ((MI) + 1) * 1024]; \
    DST[1][1] = *(const short8*)&lds[cb + (aoff ^ 32) + ((MI) + 1) * 1024];

#define MM2(AF, IP, AR, NJ) \
  acc[AR][NJ] = __builtin_amdgcn_mfma_f32_16x16x32_bf16(AF[IP][0], bfr[NJ][0], acc[AR][NJ], 0, 0, 0); \
  acc[AR][NJ] = __builtin_amdgcn_mfma_f32_16x16x32_bf16(AF[IP][1], bfr[NJ][1], acc[AR][NJ], 0, 0, 0);

#define MFMA16(AF, AR0) \
  MM2(AF, 0, AR0, 0) MM2(AF, 0, AR0, 1) MM2(AF, 0, AR0, 2) MM2(AF, 0, AR0, 3) \
  MM2(AF, 1, (AR0) + 1, 0) MM2(AF, 1, (AR0) + 1, 1) MM2(AF, 1, (AR0) + 1, 2) MM2(AF, 1, (AR0) + 1, 3)

#define LGKM_SB(N) \
  asm volatile("s_waitcnt lgkmcnt(" #N ")" ::: "memory"); \
  __builtin_amdgcn_sched_barrier(0);

  for (int S = 0; S < nkt; ++S) {
    const int cur = S & 1;
    const int oth = cur ^ 1;
    const int cb = cur * 32768;
    const int t1 = (S + 1 < nkt) ? S + 1 : nkt - 1;  // clamp: dummy tail stages
    const int t2 = (S + 2 < nkt) ? S + 2 : nkt - 1;

    // ---- tile-top reads: af rows0-1 -> afA (reads 1-4), bfr[0..3] (5-12) ----
    LD_AF(afA, 0)
#pragma unroll
    for (int nj = 0; nj < 4; ++nj) {
      bfr[nj][0] = *(const short8*)&lds[cb + boff + nj * 1024];
      bfr[nj][1] = *(const short8*)&lds[cb + (boff ^ 32) + nj * 1024];
    }
    // ---- q0: rows 0-1, stepped waits for early MFMA start ----
    STG_A(oth, t1, 0)
    LD_AF(afB, 2)                       // af rows 2-3 (reads 13-16)
    __builtin_amdgcn_s_barrier();
    __builtin_amdgcn_s_setprio(1);
    LGKM_SB(10)                         // afA + bfr0 landed
    MM2(afA, 0, 0, 0) MM2(afA, 1, 1, 0)
    LGKM_SB(8)                          // + bfr1
    MM2(afA, 0, 0, 1) MM2(afA, 1, 1, 1)
    LGKM_SB(6)                          // + bfr2
    MM2(afA, 0, 0, 2) MM2(afA, 1, 1, 2)
    LGKM_SB(4)                          // + bfr3 (afB still in flight)
    MM2(afA, 0, 0, 3) MM2(afA, 1, 1, 3)
    __builtin_amdgcn_s_setprio(0);
    __builtin_amdgcn_s_barrier();
    // ---- q1: rows 2-3 ----
    STG_A(oth, t1, 1)
    LD_AF(afA, 4)                       // af rows 4-5
    __builtin_amdgcn_s_barrier();
    __builtin_amdgcn_s_setprio(1);
    LGKM_SB(4)                          // afB landed, rows4-5 in flight
    MFMA16(afB, 2)
    __builtin_amdgcn_s_setprio(0);
    __builtin_amdgcn_s_barrier();
    // ---- q2: rows 4-5 ----
    STG_B(cur, t2, 0)
    LD_AF(afB, 6)                       // af rows 6-7
    __builtin_amdgcn_s_barrier();
    __builtin_amdgcn_s_setprio(1);
    LGKM_SB(4)                          // afA(4-5) landed, rows6-7 in flight
    MFMA16(afA, 4)
    __builtin_amdgcn_s_setprio(0);
    __builtin_amdgcn_s_barrier();
    // ---- q3: rows 6-7 ----
    STG_B(cur, t2, 1)
    __builtin_amdgcn_s_barrier();
    __builtin_amdgcn_s_setprio(1);
    LGKM_SB(0)                          // afB(6-7) landed
    MFMA16(afB, 6)
    __builtin_amdgcn_s_setprio(0);
    asm volatile("s_waitcnt vmcnt(4)" ::: "memory");  // A(S+1) landed
    __builtin_amdgcn_s_barrier();
  }

#pragma unroll
  for (int mi = 0; mi < 8; ++mi) {
    const size_t r0 = row0 + wr * 128 + mi * 16 + lq * 4;
#pragma unroll
    for (int nj = 0; nj < 4; ++nj) {
      const size_t c = col0 + wc * 64 + nj * 16 + lr;
#pragma unroll
      for (int r = 0; r < 4; ++r) {
        const float v = acc[mi][nj][r];
        if constexpr (MODE == 1)
          Cbase[(r0 + r) * 16384 + ((size_t)z << 10) + c] = f2bf(v);
        else
          Cbase[(size_t)z * PSTRIDE + (r0 + r) * 1024 + c] = f2bf(v);
      }
    }
  }
#undef LGKM_SB
#undef MFMA16
#undef MM2
#undef LD_AF
#undef STG_A
#undef STG_B
}

// ---------------------------------------------------------------------------
// h = conv7(u) * sigmoid(GP0 + GP1 + gate_b)   (gate split-K partials, bf16)
// ---------------------------------------------------------------------------
__global__ __launch_bounds__(256) void convgate2_kernel(
    const unsigned short* __restrict__ u, const float* __restrict__ conv_w,
    const unsigned short* __restrict__ gp, const float* __restrict__ gate_b,
    unsigned short* __restrict__ h) {
  const size_t idx = (size_t)blockIdx.x * 256 + threadIdx.x;
  const int d = (int)(idx & 1023);
  const int t = (int)((idx >> 10) & 2047);
  const unsigned short* up = u + idx;
  float acc = 0.f;
#pragma unroll
  for (int j = 0; j < 7; ++j) {
    const int tt = t - 6 + j;
    if (tt >= 0) acc += conv_w[d * 7 + j] * bf2f(up[(j - 6) * 1024]);
  }
  const float logit = bf2f(gp[idx]) + bf2f(gp[idx + PSTRIDE]) + gate_b[d];
  h[idx] = f2bf(acc * sigmoidf_(logit));
}

// ---------------------------------------------------------------------------
// out = x + (DP0+DP1+DP2+DP3) + down_b    (down split-K partials, bf16)
// ---------------------------------------------------------------------------
__global__ __launch_bounds__(256) void fold4_kernel(
    const float* __restrict__ x, const unsigned short* __restrict__ dp,
    const float* __restrict__ down_b, float* __restrict__ out) {
  const size_t idx = (size_t)blockIdx.x * 256 + threadIdx.x;
  const float s = bf2f(dp[idx]) + bf2f(dp[idx + PSTRIDE]) +
                  bf2f(dp[idx + 2 * PSTRIDE]) + bf2f(dp[idx + 3 * PSTRIDE]);
  out[idx] = x[idx] + s + down_b[idx & 1023];
}

// ---------------------------------------------------------------------------
// out += sigmoid(gl[row]) * sum_i P_i   (sout split-K partials, bf16)
// ---------------------------------------------------------------------------
template <int NS>
__global__ __launch_bounds__(256) void reduceNg_kernel(
    const unsigned short* __restrict__ p, const float* __restrict__ gl,
    float* __restrict__ out) {
  const size_t idx = (size_t)blockIdx.x * 256 + threadIdx.x;
  const float g = sigmoidf_(gl[idx >> 10]);
  float s = 0.f;
#pragma unroll
  for (int i = 0; i < NS; ++i) s += bf2f(p[idx + (size_t)i * PSTRIDE]);
  out[idx] += g * s;
}

// ---------------------------------------------------------------------------
// Chunked scans of u (T=2048, 16 chunks of 128), 16 decay rates each.
// ---------------------------------------------------------------------------
__global__ __launch_bounds__(256) void scan1u_kernel(
    const unsigned short* __restrict__ u, const float* __restrict__ decay_logit,
    float* __restrict__ carry) {
  const int gid = blockIdx.x * 256 + threadIdx.x;  // 0..32767
  const int d = gid & 1023;
  const int b = (gid >> 10) & 1;
  const int c = gid >> 11;
  float a[16], s[16];
#pragma unroll
  for (int k = 0; k < 16; ++k) { a[k] = sigmoidf_(decay_logit[k]); s[k] = 0.f; }
  const unsigned short* p = u + ((size_t)b * 2048 + c * 128) * 1024 + d;
#pragma unroll 2
  for (int t = 0; t < 128; ++t) {
    const float uv = bf2f(*p);
    p += 1024;
#pragma unroll
    for (int k = 0; k < 16; ++k) s[k] = fmaf(a[k], s[k], (1.f - a[k]) * uv);
  }
#pragma unroll
  for (int k = 0; k < 16; ++k)
    carry[(size_t)((c * 2 + b) * 16 + k) * 1024 + d] = s[k];
}

__global__ __launch_bounds__(256) void scan2u_kernel(
    float* __restrict__ carry, const float* __restrict__ decay_logit) {
  const int gid = blockIdx.x * 256 + threadIdx.x;  // 0..32767
  const int d = gid & 1023;
  const int k = (gid >> 10) & 15;
  const int b = gid >> 14;
  const float a = sigmoidf_(decay_logit[k]);
  float aL = a;
#pragma unroll
  for (int i = 0; i < 7; ++i) aL *= aL;  // a^128
  float s = 0.f;
#pragma unroll
  for (int c = 0; c < 16; ++c) {
    const size_t idx = (size_t)((c * 2 + b) * 16 + k) * 1024 + d;
    const float Lc = carry[idx];
    carry[idx] = s;
    s = fmaf(aL, s, Lc);
  }
}

__global__ __launch_bounds__(256) void scan3u_kernel(
    const unsigned short* __restrict__ u, const float* __restrict__ decay_logit,
    const float* __restrict__ carry, unsigned short* __restrict__ Ucat) {
  const int gid = blockIdx.x * 256 + threadIdx.x;  // 0..524287
  const int d = gid & 1023;
  const int k = (gid >> 10) & 15;
  const int b = (gid >> 14) & 1;
  const int c = gid >> 15;
  const float a = sigmoidf_(decay_logit[k]);
  const float na = 1.f - a;
  float s = carry[(size_t)((c * 2 + b) * 16 + k) * 1024 + d];
  const unsigned short* p = u + ((size_t)b * 2048 + c * 128) * 1024 + d;
  unsigned short* q = Ucat + ((size_t)b * 2048 + c * 128) * 16384 + k * 1024 + d;
#pragma unroll 4
  for (int t = 0; t < 128; ++t) {
    s = fmaf(a, s, na * bf2f(*p));
    *q = f2bf(s);
    p += 1024;
    q += 16384;
  }
}

// ---------------------------------------------------------------------------
extern "C" void kernel_launch(void* const* d_in, const int* in_sizes, int n_in,
                              void* d_out, int out_size, void* d_ws,
                              size_t ws_size, hipStream_t stream) {
  const float* x      = (const float*)d_in[0];
  const float* conv_w = (const float*)d_in[1];
  const float* gate_w = (const float*)d_in[2];
  const float* gate_b = (const float*)d_in[3];
  const float* up_w   = (const float*)d_in[4];
  const float* up_b   = (const float*)d_in[5];
  const float* down_w = (const float*)d_in[6];
  const float* down_b = (const float*)d_in[7];
  const float* sin_w  = (const float*)d_in[8];
  const float* sout_w = (const float*)d_in[9];
  const float* decay  = (const float*)d_in[10];
  const float* gl_w   = (const float*)d_in[11];
  const float* gl_b   = (const float*)d_in[12];
  float* out = (float*)d_out;
  char* ws = (char*)d_ws;

  // Workspace (MB offsets), lifetime-overlapped:
  //  phase 1 (local path):   GWT@0(2) GP@2(16,2 partials) Hb@18(8) UWT@26(4)
  //                          Mb@30(16) DWT@46(4) DP@50(32,4 partials)
  //  phase 2 (weights):      SB@0(32) OT@32(32)  [after fold]  MT@128(32)
  //  phase 3 (scan+GEMM):    Ucat@0(128)  P@160(NS partials of 8)
  //  persistent:             U@160(8, dead after scan3u) CARRY@168(2, dead
  //                          after scan3u) GL@(192 or 184)(16 KB)
  // Long-path split-K: 4 splits if ws >= 192MB+GL (peak 192MB+16KB), else 3.
  const bool big = ws_size >= (((size_t)192 << 20) + ((size_t)1 << 16));

  auto Ucat = (unsigned short*)(ws + ((size_t)0 << 20));
  auto GWT  = (unsigned short*)(ws + ((size_t)0 << 20));
  auto GP   = (unsigned short*)(ws + ((size_t)2 << 20));
  auto Hb   = (unsigned short*)(ws + ((size_t)18 << 20));
  auto UWT  = (unsigned short*)(ws + ((size_t)26 << 20));
  auto Mb   = (unsigned short*)(ws + ((size_t)30 << 20));
  auto DWT  = (unsigned short*)(ws + ((size_t)46 << 20));
  auto DP   = (unsigned short*)(ws + ((size_t)50 << 20));
  auto SB   = (unsigned short*)(ws + ((size_t)0 << 20));
  auto OT   = (unsigned short*)(ws + ((size_t)32 << 20));
  auto MT   = (unsigned short*)(ws + ((size_t)128 << 20));
  auto U    = (unsigned short*)(ws + ((size_t)160 << 20));
  auto P    = (unsigned short*)(ws + ((size_t)160 << 20));
  auto CARRY= (float*)(ws + ((size_t)168 << 20));
  auto GL   = (float*)(ws + (big ? ((size_t)192 << 20) : ((size_t)184 << 20)));

  rmsnorm_kernel<<<4096, 256, 0, stream>>>(x, gl_w, gl_b, U, GL);

  // ---- local path ----
  transpose_kernel<<<dim3(32, 32), 256, 0, stream>>>(gate_w, GWT, 1024, 1024);
  gemm_splitkP<<<dim3(32, 8, 2), 256, 0, stream>>>(U, GWT, GP, 1024, 512);
  convgate2_kernel<<<16384, 256, 0, stream>>>(U, conv_w, GP, gate_b, Hb);
  transpose_kernel<<<dim3(64, 32), 256, 0, stream>>>(up_w, UWT, 1024, 2048);
  gemm_bt<2><<<dim3(32, 16), 256, 0, stream>>>(Hb, UWT, up_b, Mb, 2048, 1024);
  transpose_kernel<<<dim3(32, 64), 256, 0, stream>>>(down_w, DWT, 2048, 1024);
  gemm256<2><<<dim3(16, 4, 4), 512, 0, stream>>>(Mb, DWT, DP, 512);
  fold4_kernel<<<16384, 256, 0, stream>>>(x, DP, down_b, out);

  // ---- composite long-path weights: MT = [sout_k^T @ sin_k^T]_k ----
  cast_kernel<<<16384, 256, 0, stream>>>(sin_w, SB);
  transpose_kernel<<<dim3(32, 512), 256, 0, stream>>>(sout_w, OT, 16384, 1024);
  gemm256<1><<<dim3(4, 4, 16), 512, 0, stream>>>(OT, SB, MT, 1024);

  // ---- 16 leaky scans of u -> Ucat (B,T,K*D) ----
  scan1u_kernel<<<128, 256, 0, stream>>>(U, decay, CARRY);
  scan2u_kernel<<<128, 256, 0, stream>>>(CARRY, decay);
  scan3u_kernel<<<2048, 256, 0, stream>>>(U, decay, CARRY, Ucat);

  // ---- long path: 256^2 8-phase split-K, bf16 partials, gated reduce ----
  if (big) {
    gemm256<0><<<dim3(16, 4, 4), 512, 0, stream>>>(Ucat, MT, P, 4096);
    reduceNg_kernel<4><<<16384, 256, 0, stream>>>(P, GL, out);
  } else {
    gemm256<0><<<dim3(16, 4, 3), 512, 0, stream>>>(Ucat, MT, P, 5504);
    reduceNg_kernel<3><<<16384, 256, 0, stream>>>(P, GL, out);
  }
}